// Round 1
// baseline (680.431 us; speedup 1.0000x reference)
//
#include <hip/hip_runtime.h>
#include <hip/hip_bf16.h>
#include <stdint.h>

// Problem constants
#define B_ 2
#define T_ 2048
#define D_ 2048
#define H_ 32
#define HKV_ 8
#define HD_ 64
#define SCALE_ 0.125f  // HD^-0.5

typedef float floatx4 __attribute__((ext_vector_type(4)));
typedef __bf16 bf16x8 __attribute__((ext_vector_type(8)));

__device__ inline floatx4 mfma16(bf16x8 a, bf16x8 b, floatx4 c) {
  return __builtin_amdgcn_mfma_f32_16x16x32_bf16(a, b, c, 0, 0, 0);
}

// RNE float -> bf16 bits
__device__ inline uint16_t f2bf(float f) {
  union { float f; uint32_t u; } x; x.f = f;
  uint32_t r = x.u + 0x7fffu + ((x.u >> 16) & 1u);
  return (uint16_t)(r >> 16);
}

// ---------------- fp32 -> bf16 convert (4 elems/thread) ----------------
__global__ __launch_bounds__(256) void cvt_bf16(const float* __restrict__ in,
                                                uint16_t* __restrict__ out, int n4) {
  int i = blockIdx.x * 256 + threadIdx.x;
  if (i >= n4) return;
  float4 v = ((const float4*)in)[i];
  union { uint16_t u[4]; uint64_t d; } o;
  o.u[0] = f2bf(v.x); o.u[1] = f2bf(v.y); o.u[2] = f2bf(v.z); o.u[3] = f2bf(v.w);
  ((uint64_t*)out)[i] = o.d;
}

// ---------------- fused QKV projection GEMM ----------------
// C = x @ W^T for W in {Wq,Wk,Wv} (N ranges [0,2048),[2048,2560),[2560,3072))
// 128x128 tile, BK=32, 4 waves (2x2), each wave 64x64 via 4x4 MFMA 16x16x32.
#define BM 128
#define BN 128
#define BK 32
#define LDT 40  // padded LDS row stride (elements)

__global__ __launch_bounds__(256) void qkv_gemm(
    const uint16_t* __restrict__ Xb, const uint16_t* __restrict__ Wqb,
    const uint16_t* __restrict__ Wkb, const uint16_t* __restrict__ Wvb,
    float* __restrict__ qf, float* __restrict__ kf, uint16_t* __restrict__ vb) {
  __shared__ __align__(16) uint16_t As[BM * LDT];
  __shared__ __align__(16) uint16_t Bs[BN * LDT];
  const int tid = threadIdx.x;
  const int m0 = blockIdx.y * BM;
  const int n0 = blockIdx.x * BN;

  const uint16_t* Wsrc; int nbase;
  if (n0 < 2048)      { Wsrc = Wqb; nbase = 0; }
  else if (n0 < 2560) { Wsrc = Wkb; nbase = 2048; }
  else                { Wsrc = Wvb; nbase = 2560; }

  const int row = tid >> 1;
  const int kof = (tid & 1) << 4;
  const uint16_t* Ag = Xb + (size_t)(m0 + row) * D_ + kof;
  const uint16_t* Bg = Wsrc + (size_t)(n0 - nbase + row) * D_ + kof;

  const int lane = tid & 63, wave = tid >> 6;
  const int wm = (wave >> 1) * 64, wn = (wave & 1) * 64;
  const int quad = lane >> 4, r16 = lane & 15;

  floatx4 acc[4][4];
  #pragma unroll
  for (int i = 0; i < 4; i++)
    #pragma unroll
    for (int j = 0; j < 4; j++) acc[i][j] = (floatx4){0.f, 0.f, 0.f, 0.f};

  for (int k0 = 0; k0 < D_; k0 += BK) {
    uint4 a0 = *(const uint4*)(Ag + k0);
    uint4 a1 = *(const uint4*)(Ag + k0 + 8);
    uint4 b0 = *(const uint4*)(Bg + k0);
    uint4 b1 = *(const uint4*)(Bg + k0 + 8);
    __syncthreads();
    *(uint4*)&As[row * LDT + kof] = a0;
    *(uint4*)&As[row * LDT + kof + 8] = a1;
    *(uint4*)&Bs[row * LDT + kof] = b0;
    *(uint4*)&Bs[row * LDT + kof + 8] = b1;
    __syncthreads();
    bf16x8 af[4], bfr[4];
    #pragma unroll
    for (int i = 0; i < 4; i++)
      af[i] = *(const bf16x8*)&As[(wm + i * 16 + r16) * LDT + quad * 8];
    #pragma unroll
    for (int j = 0; j < 4; j++)
      bfr[j] = *(const bf16x8*)&Bs[(wn + j * 16 + r16) * LDT + quad * 8];
    #pragma unroll
    for (int i = 0; i < 4; i++)
      #pragma unroll
      for (int j = 0; j < 4; j++)
        acc[i][j] = mfma16(af[i], bfr[j], acc[i][j]);
  }

  // Epilogue: scatter to (b, head, t, d). D layout: row=quad*4+r, col=r16.
  #pragma unroll
  for (int i = 0; i < 4; i++) {
    #pragma unroll
    for (int j = 0; j < 4; j++) {
      #pragma unroll
      for (int r = 0; r < 4; r++) {
        int m = m0 + wm + i * 16 + quad * 4 + r;
        int n = n0 + wn + j * 16 + r16;
        float v = acc[i][j][r];
        int b = m >> 11, t = m & (T_ - 1);
        if (n < 2048) {
          int head = n >> 6, d = n & 63;
          qf[(((size_t)b * H_ + head) * T_ + t) * HD_ + d] = v;
        } else if (n < 2560) {
          int nl = n - 2048; int head = nl >> 6, d = nl & 63;
          kf[(((size_t)b * HKV_ + head) * T_ + t) * HD_ + d] = v;
        } else {
          int nl = n - 2560; int head = nl >> 6, d = nl & 63;
          vb[(((size_t)b * HKV_ + head) * T_ + t) * HD_ + d] = f2bf(v);
        }
      }
    }
  }
}

// ---------------- O projection GEMM: out = ao @ Wo^T (plain epilogue) -----
__global__ __launch_bounds__(256) void oproj_gemm(
    const uint16_t* __restrict__ Ab, const uint16_t* __restrict__ Bb,
    float* __restrict__ C) {
  __shared__ __align__(16) uint16_t As[BM * LDT];
  __shared__ __align__(16) uint16_t Bs[BN * LDT];
  const int tid = threadIdx.x;
  const int m0 = blockIdx.y * BM;
  const int n0 = blockIdx.x * BN;
  const int row = tid >> 1;
  const int kof = (tid & 1) << 4;
  const uint16_t* Ag = Ab + (size_t)(m0 + row) * D_ + kof;
  const uint16_t* Bg = Bb + (size_t)(n0 + row) * D_ + kof;
  const int lane = tid & 63, wave = tid >> 6;
  const int wm = (wave >> 1) * 64, wn = (wave & 1) * 64;
  const int quad = lane >> 4, r16 = lane & 15;

  floatx4 acc[4][4];
  #pragma unroll
  for (int i = 0; i < 4; i++)
    #pragma unroll
    for (int j = 0; j < 4; j++) acc[i][j] = (floatx4){0.f, 0.f, 0.f, 0.f};

  for (int k0 = 0; k0 < D_; k0 += BK) {
    uint4 a0 = *(const uint4*)(Ag + k0);
    uint4 a1 = *(const uint4*)(Ag + k0 + 8);
    uint4 b0 = *(const uint4*)(Bg + k0);
    uint4 b1 = *(const uint4*)(Bg + k0 + 8);
    __syncthreads();
    *(uint4*)&As[row * LDT + kof] = a0;
    *(uint4*)&As[row * LDT + kof + 8] = a1;
    *(uint4*)&Bs[row * LDT + kof] = b0;
    *(uint4*)&Bs[row * LDT + kof + 8] = b1;
    __syncthreads();
    bf16x8 af[4], bfr[4];
    #pragma unroll
    for (int i = 0; i < 4; i++)
      af[i] = *(const bf16x8*)&As[(wm + i * 16 + r16) * LDT + quad * 8];
    #pragma unroll
    for (int j = 0; j < 4; j++)
      bfr[j] = *(const bf16x8*)&Bs[(wn + j * 16 + r16) * LDT + quad * 8];
    #pragma unroll
    for (int i = 0; i < 4; i++)
      #pragma unroll
      for (int j = 0; j < 4; j++)
        acc[i][j] = mfma16(af[i], bfr[j], acc[i][j]);
  }
  #pragma unroll
  for (int i = 0; i < 4; i++)
    #pragma unroll
    for (int j = 0; j < 4; j++)
      #pragma unroll
      for (int r = 0; r < 4; r++) {
        int m = m0 + wm + i * 16 + quad * 4 + r;
        int n = n0 + wn + j * 16 + r16;
        C[(size_t)m * D_ + n] = acc[i][j][r];
      }
}

// ---------------- RMSNorm + RoPE (one wave per 64-elem head row) ----------
__global__ __launch_bounds__(256) void rmsrope(const float* __restrict__ src,
                                               uint16_t* __restrict__ dst,
                                               const float* __restrict__ w) {
  const int wave = threadIdx.x >> 6, lane = threadIdx.x & 63;
  const int rid = blockIdx.x * 4 + wave;
  const int t = rid & (T_ - 1);
  float v = src[(size_t)rid * HD_ + lane];
  float ss = v * v;
  #pragma unroll
  for (int off = 32; off; off >>= 1) ss += __shfl_xor(ss, off);
  float inv = rsqrtf(ss * (1.0f / HD_) + 1e-6f);
  float vn = v * inv * w[lane];
  int p = lane >> 1;
  float freq = powf(3.0f, -(float)(2 * p) / 64.0f);
  float f = (float)t * freq;
  float s, c;
  sincosf(f, &s, &c);
  float other = __shfl_xor(vn, 1);
  float out = (lane & 1) ? (other * s + vn * c) : (vn * c - other * s);
  dst[(size_t)rid * HD_ + lane] = f2bf(out);
}

// ---------------- Flash attention: 16 q-rows per wave, MFMA QK^T + PV -----
__global__ __launch_bounds__(256) void attn(const uint16_t* __restrict__ qb,
                                            const uint16_t* __restrict__ kb,
                                            const uint16_t* __restrict__ vbuf,
                                            uint16_t* __restrict__ ao) {
  const int wave = threadIdx.x >> 6, lane = threadIdx.x & 63;
  const int quad = lane >> 4, r16 = lane & 15;
  const int qt = blockIdx.x, h = blockIdx.y, b = blockIdx.z;
  const int R = qt * 64 + wave * 16;  // wave's first q row
  const int kvh = h >> 2;             // GQA: 4 q heads per kv head

  const uint16_t* Q = qb + (((size_t)b * H_ + h) * T_ + R) * HD_;
  const uint16_t* K = kb + ((size_t)b * HKV_ + kvh) * T_ * HD_;
  const uint16_t* V = vbuf + ((size_t)b * HKV_ + kvh) * T_ * HD_;

  // Q fragments held in registers across whole k-loop (A layout: m=r16, k=quad*8+j)
  bf16x8 aq0 = *(const bf16x8*)(Q + r16 * HD_ + quad * 8);
  bf16x8 aq1 = *(const bf16x8*)(Q + r16 * HD_ + 32 + quad * 8);

  __shared__ __align__(16) uint16_t Ps[4][16 * 40];  // per-wave P staging, rows padded to 40
  uint16_t* myPs = Ps[wave];

  float m_i[4], l_i[4];
  floatx4 o[4];
  #pragma unroll
  for (int r = 0; r < 4; r++) { m_i[r] = -1e30f; l_i[r] = 0.f; }
  #pragma unroll
  for (int jn = 0; jn < 4; jn++) o[jn] = (floatx4){0.f, 0.f, 0.f, 0.f};

  const int kend = R + 15;
  for (int kt = 0; kt <= kend; kt += 32) {
    // ---- S = Q K^T for 32 k-columns (two 16-wide MFMA tiles) ----
    floatx4 s0 = (floatx4){0.f, 0.f, 0.f, 0.f};
    floatx4 s1 = (floatx4){0.f, 0.f, 0.f, 0.f};
    {
      const uint16_t* Kp = K + (size_t)(kt + r16) * HD_ + quad * 8;
      bf16x8 k0 = *(const bf16x8*)(Kp);
      bf16x8 k1 = *(const bf16x8*)(Kp + 32);
      s0 = mfma16(aq0, k0, s0);
      s0 = mfma16(aq1, k1, s0);
      const uint16_t* Kp2 = K + (size_t)(kt + 16 + r16) * HD_ + quad * 8;
      bf16x8 k2 = *(const bf16x8*)(Kp2);
      bf16x8 k3 = *(const bf16x8*)(Kp2 + 32);
      s1 = mfma16(aq0, k2, s1);
      s1 = mfma16(aq1, k3, s1);
    }
    // ---- scale + causal mask + online softmax (rows live in quad groups) ----
    float rm[4], p0[4], p1[4];
    #pragma unroll
    for (int r = 0; r < 4; r++) {
      int qrow = R + quad * 4 + r;
      float v0 = (kt + r16 <= qrow) ? s0[r] * SCALE_ : -1e30f;
      float v1 = (kt + 16 + r16 <= qrow) ? s1[r] * SCALE_ : -1e30f;
      p0[r] = v0; p1[r] = v1;
      rm[r] = fmaxf(v0, v1);
    }
    #pragma unroll
    for (int r = 0; r < 4; r++)
      #pragma unroll
      for (int off = 8; off; off >>= 1) rm[r] = fmaxf(rm[r], __shfl_xor(rm[r], off));
    float alpha[4], rs[4];
    #pragma unroll
    for (int r = 0; r < 4; r++) {
      float mn = fmaxf(m_i[r], rm[r]);
      alpha[r] = __expf(m_i[r] - mn);
      m_i[r] = mn;
      p0[r] = __expf(p0[r] - mn);
      p1[r] = __expf(p1[r] - mn);
      rs[r] = p0[r] + p1[r];
    }
    #pragma unroll
    for (int r = 0; r < 4; r++) {
      #pragma unroll
      for (int off = 8; off; off >>= 1) rs[r] += __shfl_xor(rs[r], off);
      l_i[r] = l_i[r] * alpha[r] + rs[r];
    }
    #pragma unroll
    for (int jn = 0; jn < 4; jn++)
      #pragma unroll
      for (int r = 0; r < 4; r++) o[jn][r] *= alpha[r];

    // ---- P: C-layout -> A-layout via per-wave LDS ----
    #pragma unroll
    for (int r = 0; r < 4; r++) {
      myPs[(quad * 4 + r) * 40 + r16] = f2bf(p0[r]);
      myPs[(quad * 4 + r) * 40 + 16 + r16] = f2bf(p1[r]);
    }
    __asm__ __volatile__("s_waitcnt lgkmcnt(0)" ::: "memory");
    bf16x8 ap = *(const bf16x8*)&myPs[r16 * 40 + quad * 8];

    // ---- O += P V  (B layout: k=quad*8+j rows of V, n=r16 col) ----
    #pragma unroll
    for (int jn = 0; jn < 4; jn++) {
      union { uint16_t u[8]; bf16x8 v; } bvv;
      #pragma unroll
      for (int j = 0; j < 8; j++)
        bvv.u[j] = V[(size_t)(kt + quad * 8 + j) * HD_ + jn * 16 + r16];
      o[jn] = mfma16(ap, bvv.v, o[jn]);
    }
  }
  // ---- epilogue: ao[b][t][h*64 + d] bf16 ----
  #pragma unroll
  for (int jn = 0; jn < 4; jn++)
    #pragma unroll
    for (int r = 0; r < 4; r++) {
      int t = R + quad * 4 + r;
      float val = o[jn][r] / l_i[r];
      ao[((size_t)b * T_ + t) * (H_ * HD_) + h * HD_ + jn * 16 + r16] = f2bf(val);
    }
}

extern "C" void kernel_launch(void* const* d_in, const int* in_sizes, int n_in,
                              void* d_out, int out_size, void* d_ws, size_t ws_size,
                              hipStream_t stream) {
  const float* x  = (const float*)d_in[0];
  const float* Wq = (const float*)d_in[1];
  const float* Wk = (const float*)d_in[2];
  const float* Wv = (const float*)d_in[3];
  const float* Wo = (const float*)d_in[4];
  const float* qw = (const float*)d_in[5];
  const float* kw = (const float*)d_in[6];
  float* out = (float*)d_out;

  char* ws = (char*)d_ws;
  // workspace layout (100 MB total); xb region is reused for attention output
  uint16_t* xb  = (uint16_t*)(ws);               // 16 MB  x bf16 (later: ao bf16)
  uint16_t* wqb = (uint16_t*)(ws + 16777216);    // 8 MB
  uint16_t* wkb = (uint16_t*)(ws + 25165824);    // 2 MB
  uint16_t* wvb = (uint16_t*)(ws + 27262976);    // 2 MB
  uint16_t* wob = (uint16_t*)(ws + 29360128);    // 8 MB
  float*    qf  = (float*)   (ws + 37748736);    // 32 MB  q fp32 (b,h,t,d)
  float*    kf  = (float*)   (ws + 71303168);    // 8 MB   k fp32 (b,kvh,t,d)
  uint16_t* qbf = (uint16_t*)(ws + 79691776);    // 16 MB  q bf16 post norm+rope
  uint16_t* kbf = (uint16_t*)(ws + 96468992);    // 4 MB
  uint16_t* vbf = (uint16_t*)(ws + 100663296);   // 4 MB   v bf16
  uint16_t* aob = xb;                            // attention out bf16 (b,t,h*hd)

  cvt_bf16<<<8192, 256, 0, stream>>>(x, xb, 2097152);
  cvt_bf16<<<4096, 256, 0, stream>>>(Wq, wqb, 1048576);
  cvt_bf16<<<1024, 256, 0, stream>>>(Wk, wkb, 262144);
  cvt_bf16<<<1024, 256, 0, stream>>>(Wv, wvb, 262144);
  cvt_bf16<<<4096, 256, 0, stream>>>(Wo, wob, 1048576);

  qkv_gemm<<<dim3(24, 32), 256, 0, stream>>>(xb, wqb, wkb, wvb, qf, kf, vbf);

  rmsrope<<<32768, 256, 0, stream>>>(qf, qbf, qw);  // B*H*T/4 blocks
  rmsrope<<<8192, 256, 0, stream>>>(kf, kbf, kw);   // B*HKV*T/4 blocks

  attn<<<dim3(32, 32, 2), 256, 0, stream>>>(qbf, kbf, vbf, aob);

  oproj_gemm<<<dim3(16, 32), 256, 0, stream>>>(aob, wob, out);
}

// Round 2
// 466.599 us; speedup vs baseline: 1.4583x; 1.4583x over previous
//
#include <hip/hip_runtime.h>
#include <hip/hip_bf16.h>
#include <stdint.h>

// Problem constants
#define B_ 2
#define T_ 2048
#define D_ 2048
#define H_ 32
#define HKV_ 8
#define HD_ 64
#define SCALE_ 0.125f  // HD^-0.5

typedef float floatx4 __attribute__((ext_vector_type(4)));
typedef __bf16 bf16x8 __attribute__((ext_vector_type(8)));

__device__ inline floatx4 mfma16(bf16x8 a, bf16x8 b, floatx4 c) {
  return __builtin_amdgcn_mfma_f32_16x16x32_bf16(a, b, c, 0, 0, 0);
}

// RNE float -> bf16 bits
__device__ inline uint16_t f2bf(float f) {
  union { float f; uint32_t u; } x; x.f = f;
  uint32_t r = x.u + 0x7fffu + ((x.u >> 16) & 1u);
  return (uint16_t)(r >> 16);
}

// ---------------- fp32 -> bf16 convert (4 elems/thread) ----------------
__global__ __launch_bounds__(256) void cvt_bf16(const float* __restrict__ in,
                                                uint16_t* __restrict__ out, int n4) {
  int i = blockIdx.x * 256 + threadIdx.x;
  if (i >= n4) return;
  float4 v = ((const float4*)in)[i];
  union { uint16_t u[4]; uint64_t d; } o;
  o.u[0] = f2bf(v.x); o.u[1] = f2bf(v.y); o.u[2] = f2bf(v.z); o.u[3] = f2bf(v.w);
  ((uint64_t*)out)[i] = o.d;
}

// ---------------- fused QKV projection GEMM ----------------
#define BM 128
#define BN 128
#define BK 32
#define LDT 40  // padded LDS row stride (elements)

__global__ __launch_bounds__(256) void qkv_gemm(
    const uint16_t* __restrict__ Xb, const uint16_t* __restrict__ Wqb,
    const uint16_t* __restrict__ Wkb, const uint16_t* __restrict__ Wvb,
    float* __restrict__ qf, float* __restrict__ kf, uint16_t* __restrict__ vt) {
  __shared__ __align__(16) uint16_t As[BM * LDT];
  __shared__ __align__(16) uint16_t Bs[BN * LDT];
  const int tid = threadIdx.x;
  const int m0 = blockIdx.y * BM;
  const int n0 = blockIdx.x * BN;

  const uint16_t* Wsrc; int nbase;
  if (n0 < 2048)      { Wsrc = Wqb; nbase = 0; }
  else if (n0 < 2560) { Wsrc = Wkb; nbase = 2048; }
  else                { Wsrc = Wvb; nbase = 2560; }

  const int row = tid >> 1;
  const int kof = (tid & 1) << 4;
  const uint16_t* Ag = Xb + (size_t)(m0 + row) * D_ + kof;
  const uint16_t* Bg = Wsrc + (size_t)(n0 - nbase + row) * D_ + kof;

  const int lane = tid & 63, wave = tid >> 6;
  const int wm = (wave >> 1) * 64, wn = (wave & 1) * 64;
  const int quad = lane >> 4, r16 = lane & 15;

  floatx4 acc[4][4];
  #pragma unroll
  for (int i = 0; i < 4; i++)
    #pragma unroll
    for (int j = 0; j < 4; j++) acc[i][j] = (floatx4){0.f, 0.f, 0.f, 0.f};

  for (int k0 = 0; k0 < D_; k0 += BK) {
    uint4 a0 = *(const uint4*)(Ag + k0);
    uint4 a1 = *(const uint4*)(Ag + k0 + 8);
    uint4 b0 = *(const uint4*)(Bg + k0);
    uint4 b1 = *(const uint4*)(Bg + k0 + 8);
    __syncthreads();
    *(uint4*)&As[row * LDT + kof] = a0;
    *(uint4*)&As[row * LDT + kof + 8] = a1;
    *(uint4*)&Bs[row * LDT + kof] = b0;
    *(uint4*)&Bs[row * LDT + kof + 8] = b1;
    __syncthreads();
    bf16x8 af[4], bfr[4];
    #pragma unroll
    for (int i = 0; i < 4; i++)
      af[i] = *(const bf16x8*)&As[(wm + i * 16 + r16) * LDT + quad * 8];
    #pragma unroll
    for (int j = 0; j < 4; j++)
      bfr[j] = *(const bf16x8*)&Bs[(wn + j * 16 + r16) * LDT + quad * 8];
    #pragma unroll
    for (int i = 0; i < 4; i++)
      #pragma unroll
      for (int j = 0; j < 4; j++)
        acc[i][j] = mfma16(af[i], bfr[j], acc[i][j]);
  }

  // Epilogue scatter. D layout: row=quad*4+r, col=r16.
  // V is written TRANSPOSED: (b, kvh, d, t) so attention can read Vt rows.
  #pragma unroll
  for (int i = 0; i < 4; i++) {
    #pragma unroll
    for (int j = 0; j < 4; j++) {
      #pragma unroll
      for (int r = 0; r < 4; r++) {
        int m = m0 + wm + i * 16 + quad * 4 + r;
        int n = n0 + wn + j * 16 + r16;
        float v = acc[i][j][r];
        int b = m >> 11, t = m & (T_ - 1);
        if (n < 2048) {
          int head = n >> 6, d = n & 63;
          qf[(((size_t)b * H_ + head) * T_ + t) * HD_ + d] = v;
        } else if (n < 2560) {
          int nl = n - 2048; int head = nl >> 6, d = nl & 63;
          kf[(((size_t)b * HKV_ + head) * T_ + t) * HD_ + d] = v;
        } else {
          int nl = n - 2560; int head = nl >> 6, d = nl & 63;
          vt[(((size_t)b * HKV_ + head) * HD_ + d) * T_ + t] = f2bf(v);
        }
      }
    }
  }
}

// ---------------- O projection GEMM: out = ao @ Wo^T ----------------------
__global__ __launch_bounds__(256) void oproj_gemm(
    const uint16_t* __restrict__ Ab, const uint16_t* __restrict__ Bb,
    float* __restrict__ C) {
  __shared__ __align__(16) uint16_t As[BM * LDT];
  __shared__ __align__(16) uint16_t Bs[BN * LDT];
  const int tid = threadIdx.x;
  const int m0 = blockIdx.y * BM;
  const int n0 = blockIdx.x * BN;
  const int row = tid >> 1;
  const int kof = (tid & 1) << 4;
  const uint16_t* Ag = Ab + (size_t)(m0 + row) * D_ + kof;
  const uint16_t* Bg = Bb + (size_t)(n0 + row) * D_ + kof;
  const int lane = tid & 63, wave = tid >> 6;
  const int wm = (wave >> 1) * 64, wn = (wave & 1) * 64;
  const int quad = lane >> 4, r16 = lane & 15;

  floatx4 acc[4][4];
  #pragma unroll
  for (int i = 0; i < 4; i++)
    #pragma unroll
    for (int j = 0; j < 4; j++) acc[i][j] = (floatx4){0.f, 0.f, 0.f, 0.f};

  for (int k0 = 0; k0 < D_; k0 += BK) {
    uint4 a0 = *(const uint4*)(Ag + k0);
    uint4 a1 = *(const uint4*)(Ag + k0 + 8);
    uint4 b0 = *(const uint4*)(Bg + k0);
    uint4 b1 = *(const uint4*)(Bg + k0 + 8);
    __syncthreads();
    *(uint4*)&As[row * LDT + kof] = a0;
    *(uint4*)&As[row * LDT + kof + 8] = a1;
    *(uint4*)&Bs[row * LDT + kof] = b0;
    *(uint4*)&Bs[row * LDT + kof + 8] = b1;
    __syncthreads();
    bf16x8 af[4], bfr[4];
    #pragma unroll
    for (int i = 0; i < 4; i++)
      af[i] = *(const bf16x8*)&As[(wm + i * 16 + r16) * LDT + quad * 8];
    #pragma unroll
    for (int j = 0; j < 4; j++)
      bfr[j] = *(const bf16x8*)&Bs[(wn + j * 16 + r16) * LDT + quad * 8];
    #pragma unroll
    for (int i = 0; i < 4; i++)
      #pragma unroll
      for (int j = 0; j < 4; j++)
        acc[i][j] = mfma16(af[i], bfr[j], acc[i][j]);
  }
  #pragma unroll
  for (int i = 0; i < 4; i++)
    #pragma unroll
    for (int j = 0; j < 4; j++)
      #pragma unroll
      for (int r = 0; r < 4; r++) {
        int m = m0 + wm + i * 16 + quad * 4 + r;
        int n = n0 + wn + j * 16 + r16;
        C[(size_t)m * D_ + n] = acc[i][j][r];
      }
}

// ---------------- RMSNorm + RoPE (one wave per 64-elem head row) ----------
__global__ __launch_bounds__(256) void rmsrope(const float* __restrict__ src,
                                               uint16_t* __restrict__ dst,
                                               const float* __restrict__ w) {
  const int wave = threadIdx.x >> 6, lane = threadIdx.x & 63;
  const int rid = blockIdx.x * 4 + wave;
  const int t = rid & (T_ - 1);
  float v = src[(size_t)rid * HD_ + lane];
  float ss = v * v;
  #pragma unroll
  for (int off = 32; off; off >>= 1) ss += __shfl_xor(ss, off);
  float inv = rsqrtf(ss * (1.0f / HD_) + 1e-6f);
  float vn = v * inv * w[lane];
  int p = lane >> 1;
  // freq = 3^(-2p/64) = exp2(-p * log2(3)/32)
  float freq = exp2f((float)p * -0.0495300781f);
  float f = (float)t * freq;
  float s, c;
  sincosf(f, &s, &c);
  float other = __shfl_xor(vn, 1);
  float out = (lane & 1) ? (other * s + vn * c) : (vn * c - other * s);
  dst[(size_t)rid * HD_ + lane] = f2bf(out);
}

// ---------------- Flash attention v2 -------------------------------------
// Block: 128 q rows (4 waves x 32 rows, each as two 16-row subtiles).
// K-tile (64x64) and transposed V-tile (64 d x 64 k) staged in LDS, shared
// by all 4 waves. Static-max softmax (m=8 hard bound via Cauchy-Schwarz on
// RMS-normed q,k): no max reduce, no alpha rescale; l reduced once at end.
#define AT_PAD 72  // LDS row stride (elems); 36 dwords -> conflict-benign

__global__ __launch_bounds__(256) void attn(const uint16_t* __restrict__ qb,
                                            const uint16_t* __restrict__ kb,
                                            const uint16_t* __restrict__ vtb,
                                            uint16_t* __restrict__ ao) {
  const int wave = threadIdx.x >> 6, lane = threadIdx.x & 63;
  const int quad = lane >> 4, r16 = lane & 15;
  const int qt = (int)gridDim.x - 1 - blockIdx.x;  // heavy blocks first
  const int h = blockIdx.y, b = blockIdx.z;
  const int kvh = h >> 2;
  const int q0 = qt * 128;
  const int Rw = q0 + wave * 32;  // wave's first q row

  const uint16_t* Q  = qb  + ((size_t)b * H_ + h) * T_ * HD_;
  const uint16_t* K  = kb  + ((size_t)b * HKV_ + kvh) * T_ * HD_;
  const uint16_t* Vt = vtb + ((size_t)b * HKV_ + kvh) * (size_t)HD_ * T_;

  __shared__ __align__(16) uint16_t Kl[64 * AT_PAD];
  __shared__ __align__(16) uint16_t Vl[64 * AT_PAD];
  __shared__ __align__(16) uint16_t Pl[4][32 * AT_PAD];
  uint16_t* myP = Pl[wave];

  // Q A-frags, held for the whole loop: [subtile m][khalf]
  bf16x8 aq[2][2];
  #pragma unroll
  for (int m = 0; m < 2; m++)
    #pragma unroll
    for (int hh = 0; hh < 2; hh++)
      aq[m][hh] = *(const bf16x8*)(Q + (size_t)(Rw + m * 16 + r16) * HD_ + hh * 32 + quad * 8);

  floatx4 o[2][4];   // [subtile][d-chunk]
  float l[2][4];     // per-lane partial row sums: rows Rw+m*16+quad*4+r
  #pragma unroll
  for (int m = 0; m < 2; m++) {
    #pragma unroll
    for (int j = 0; j < 4; j++) o[m][j] = (floatx4){0.f, 0.f, 0.f, 0.f};
    #pragma unroll
    for (int r = 0; r < 4; r++) l[m][r] = 0.f;
  }

  const int wkend = Rw + 31;
  const int iters = (q0 + 128) / 64;  // 2*qt + 2
  const int srow = threadIdx.x >> 2, sseg = threadIdx.x & 3;

  for (int it = 0; it < iters; it++) {
    const int kt = it * 64;
    // ---- cooperative staging: K rows + Vt rows, coalesced 16B loads ----
    {
      const uint16_t* kg = K + (size_t)(kt + srow) * HD_ + sseg * 16;
      uint4 k0 = *(const uint4*)kg;
      uint4 k1 = *(const uint4*)(kg + 8);
      const uint16_t* vg = Vt + (size_t)srow * T_ + kt + sseg * 16;
      uint4 v0 = *(const uint4*)vg;
      uint4 v1 = *(const uint4*)(vg + 8);
      __syncthreads();  // previous iter's consumers done before overwrite
      *(uint4*)&Kl[srow * AT_PAD + sseg * 16] = k0;
      *(uint4*)&Kl[srow * AT_PAD + sseg * 16 + 8] = k1;
      *(uint4*)&Vl[srow * AT_PAD + sseg * 16] = v0;
      *(uint4*)&Vl[srow * AT_PAD + sseg * 16 + 8] = v1;
      __syncthreads();
    }
    if (kt > wkend) continue;  // wave past its causal range (barriers already hit)

    const bool need_mask = (kt + 63) > Rw;

    // ---- S = Q K^T : [subtile][n-chunk] ----
    floatx4 s[2][4];
    #pragma unroll
    for (int m = 0; m < 2; m++)
      #pragma unroll
      for (int nc = 0; nc < 4; nc++) s[m][nc] = (floatx4){0.f, 0.f, 0.f, 0.f};
    #pragma unroll
    for (int nc = 0; nc < 4; nc++) {
      bf16x8 kf0 = *(const bf16x8*)&Kl[(nc * 16 + r16) * AT_PAD + quad * 8];
      bf16x8 kf1 = *(const bf16x8*)&Kl[(nc * 16 + r16) * AT_PAD + 32 + quad * 8];
      #pragma unroll
      for (int m = 0; m < 2; m++) {
        s[m][nc] = mfma16(aq[m][0], kf0, s[m][nc]);
        s[m][nc] = mfma16(aq[m][1], kf1, s[m][nc]);
      }
    }

    // ---- static-max softmax: p = exp(s*0.125 - 8), causal mask in tail ----
    #pragma unroll
    for (int m = 0; m < 2; m++) {
      #pragma unroll
      for (int nc = 0; nc < 4; nc++) {
        #pragma unroll
        for (int r = 0; r < 4; r++) {
          float pv = __expf(fmaf(s[m][nc][r], SCALE_, -8.0f));
          if (need_mask) {
            int col = kt + nc * 16 + r16;
            int rowq = Rw + m * 16 + quad * 4 + r;
            pv = (col <= rowq) ? pv : 0.f;
          }
          l[m][r] += pv;
          myP[(m * 16 + quad * 4 + r) * AT_PAD + nc * 16 + r16] = f2bf(pv);
        }
      }
    }
    __asm__ __volatile__("s_waitcnt lgkmcnt(0)" ::: "memory");

    // ---- O += P V : P A-frags from per-wave LDS, V B-frags from shared ----
    bf16x8 ap[2][2];
    #pragma unroll
    for (int m = 0; m < 2; m++) {
      ap[m][0] = *(const bf16x8*)&myP[(m * 16 + r16) * AT_PAD + quad * 8];
      ap[m][1] = *(const bf16x8*)&myP[(m * 16 + r16) * AT_PAD + 32 + quad * 8];
    }
    #pragma unroll
    for (int jn = 0; jn < 4; jn++) {
      bf16x8 vf0 = *(const bf16x8*)&Vl[(jn * 16 + r16) * AT_PAD + quad * 8];
      bf16x8 vf1 = *(const bf16x8*)&Vl[(jn * 16 + r16) * AT_PAD + 32 + quad * 8];
      #pragma unroll
      for (int m = 0; m < 2; m++) {
        o[m][jn] = mfma16(ap[m][0], vf0, o[m][jn]);
        o[m][jn] = mfma16(ap[m][1], vf1, o[m][jn]);
      }
    }
  }

  // ---- final l reduction across the 16 n-lanes, then normalize+store ----
  #pragma unroll
  for (int m = 0; m < 2; m++)
    #pragma unroll
    for (int r = 0; r < 4; r++) {
      #pragma unroll
      for (int off = 8; off; off >>= 1) l[m][r] += __shfl_xor(l[m][r], off);
    }
  #pragma unroll
  for (int m = 0; m < 2; m++)
    #pragma unroll
    for (int jn = 0; jn < 4; jn++)
      #pragma unroll
      for (int r = 0; r < 4; r++) {
        int t = Rw + m * 16 + quad * 4 + r;
        float val = o[m][jn][r] / l[m][r];
        ao[((size_t)b * T_ + t) * (H_ * HD_) + h * HD_ + jn * 16 + r16] = f2bf(val);
      }
}

extern "C" void kernel_launch(void* const* d_in, const int* in_sizes, int n_in,
                              void* d_out, int out_size, void* d_ws, size_t ws_size,
                              hipStream_t stream) {
  const float* x  = (const float*)d_in[0];
  const float* Wq = (const float*)d_in[1];
  const float* Wk = (const float*)d_in[2];
  const float* Wv = (const float*)d_in[3];
  const float* Wo = (const float*)d_in[4];
  const float* qw = (const float*)d_in[5];
  const float* kw = (const float*)d_in[6];
  float* out = (float*)d_out;

  char* ws = (char*)d_ws;
  uint16_t* xb  = (uint16_t*)(ws);               // 16 MB  x bf16 (later: ao bf16)
  uint16_t* wqb = (uint16_t*)(ws + 16777216);    // 8 MB
  uint16_t* wkb = (uint16_t*)(ws + 25165824);    // 2 MB
  uint16_t* wvb = (uint16_t*)(ws + 27262976);    // 2 MB
  uint16_t* wob = (uint16_t*)(ws + 29360128);    // 8 MB
  float*    qf  = (float*)   (ws + 37748736);    // 32 MB  q fp32 (b,h,t,d)
  float*    kf  = (float*)   (ws + 71303168);    // 8 MB   k fp32 (b,kvh,t,d)
  uint16_t* qbf = (uint16_t*)(ws + 79691776);    // 16 MB  q bf16 post norm+rope
  uint16_t* kbf = (uint16_t*)(ws + 96468992);    // 4 MB
  uint16_t* vtb = (uint16_t*)(ws + 100663296);   // 4 MB   V^T bf16 (b,kvh,d,t)
  uint16_t* aob = xb;

  cvt_bf16<<<8192, 256, 0, stream>>>(x, xb, 2097152);
  cvt_bf16<<<4096, 256, 0, stream>>>(Wq, wqb, 1048576);
  cvt_bf16<<<1024, 256, 0, stream>>>(Wk, wkb, 262144);
  cvt_bf16<<<1024, 256, 0, stream>>>(Wv, wvb, 262144);
  cvt_bf16<<<4096, 256, 0, stream>>>(Wo, wob, 1048576);

  qkv_gemm<<<dim3(24, 32), 256, 0, stream>>>(xb, wqb, wkb, wvb, qf, kf, vtb);

  rmsrope<<<32768, 256, 0, stream>>>(qf, qbf, qw);
  rmsrope<<<8192, 256, 0, stream>>>(kf, kbf, kw);

  attn<<<dim3(16, 32, 2), 256, 0, stream>>>(qbf, kbf, vtb, aob);

  oproj_gemm<<<dim3(16, 32), 256, 0, stream>>>(aob, wob, out);
}

// Round 3
// 420.087 us; speedup vs baseline: 1.6197x; 1.1107x over previous
//
#include <hip/hip_runtime.h>
#include <hip/hip_bf16.h>
#include <stdint.h>

// Problem constants
#define B_ 2
#define T_ 2048
#define D_ 2048
#define H_ 32
#define HKV_ 8
#define HD_ 64
#define SCALE_ 0.125f  // HD^-0.5

typedef float floatx4 __attribute__((ext_vector_type(4)));
typedef __bf16 bf16x8 __attribute__((ext_vector_type(8)));

__device__ inline floatx4 mfma16(bf16x8 a, bf16x8 b, floatx4 c) {
  return __builtin_amdgcn_mfma_f32_16x16x32_bf16(a, b, c, 0, 0, 0);
}

// RNE float -> bf16 bits
__device__ inline uint16_t f2bf(float f) {
  union { float f; uint32_t u; } x; x.f = f;
  uint32_t r = x.u + 0x7fffu + ((x.u >> 16) & 1u);
  return (uint16_t)(r >> 16);
}

// packed pair: lo = a, hi = b
__device__ inline uint32_t f2bf_pk(float a, float b) {
#if __has_builtin(__builtin_amdgcn_cvt_pk_bf16_f32)
  auto pk = __builtin_amdgcn_cvt_pk_bf16_f32(a, b);
  return __builtin_bit_cast(uint32_t, pk);
#else
  return (uint32_t)f2bf(a) | ((uint32_t)f2bf(b) << 16);
#endif
}

__device__ inline float fast_exp2(float x) {
#if __has_builtin(__builtin_amdgcn_exp2f)
  return __builtin_amdgcn_exp2f(x);
#else
  return __expf(x * 0.69314718056f);
#endif
}

#if __has_builtin(__builtin_amdgcn_global_load_lds)
#define HAVE_ASYNC_LDS 1
typedef const __attribute__((address_space(1))) uint32_t* gas1_u32;
typedef __attribute__((address_space(3))) uint32_t* las3_u32;
__device__ inline void g2lds16(const uint16_t* g, uint16_t* l) {
  __builtin_amdgcn_global_load_lds((gas1_u32)(const void*)g, (las3_u32)(void*)l, 16, 0, 0);
}
#endif

// ---------------- merged fp32 -> bf16 convert (4 elems/thread) ------------
// segments (float4 groups): x 2097152 | Wq 1048576 | Wk 262144 | Wv 262144 | Wo 1048576
__global__ __launch_bounds__(256) void cvt_all(
    const float* __restrict__ x, const float* __restrict__ wq,
    const float* __restrict__ wk, const float* __restrict__ wv,
    const float* __restrict__ wo,
    uint16_t* __restrict__ xb, uint16_t* __restrict__ wqb,
    uint16_t* __restrict__ wkb, uint16_t* __restrict__ wvb,
    uint16_t* __restrict__ wob) {
  int i = blockIdx.x * 256 + threadIdx.x;
  const float* src; uint16_t* dst; int off;
  if (i < 2097152)      { src = x;  dst = xb;  off = i; }
  else if (i < 3145728) { src = wq; dst = wqb; off = i - 2097152; }
  else if (i < 3407872) { src = wk; dst = wkb; off = i - 3145728; }
  else if (i < 3670016) { src = wv; dst = wvb; off = i - 3407872; }
  else                  { src = wo; dst = wob; off = i - 3670016; }
  float4 v = ((const float4*)src)[off];
  uint64_t packed = (uint64_t)f2bf_pk(v.x, v.y) | ((uint64_t)f2bf_pk(v.z, v.w) << 32);
  ((uint64_t*)dst)[off] = packed;
}

// ---------------- GEMM common: m97-style staging ----------------
// 128x128 tile, BK=32, unpadded 128x32 LDS tiles (stride 32 elems),
// global_load_lds width=16: wave w stages rows [chunk*16, chunk*16+16),
// lane l -> row chunk*16 + (l>>2), k-cols (l&3)*8 .. +8. LDS = base + lane*16B.
#define BM 128
#define BN 128
#define BK 32

__device__ inline void stage_tile(const uint16_t* gbase, uint16_t* lds,
                                  int k0, int wave, int lane) {
#ifdef HAVE_ASYNC_LDS
  #pragma unroll
  for (int c = 0; c < 2; c++) {
    int chunk = wave * 2 + c;
    g2lds16(gbase + (size_t)(chunk * 16 + (lane >> 2)) * D_ + k0 + (lane & 3) * 8,
            lds + chunk * 512 + lane * 8);
  }
#else
  int tid = wave * 64 + lane;
  int r = tid >> 1, kof = (tid & 1) * 16;
  *(uint4*)&lds[r * 32 + kof]     = *(const uint4*)(gbase + (size_t)r * D_ + k0 + kof);
  *(uint4*)&lds[r * 32 + kof + 8] = *(const uint4*)(gbase + (size_t)r * D_ + k0 + kof + 8);
#endif
}

// ---------------- fused QKV projection GEMM ----------------
__global__ __launch_bounds__(256) void qkv_gemm(
    const uint16_t* __restrict__ Xb, const uint16_t* __restrict__ Wqb,
    const uint16_t* __restrict__ Wkb, const uint16_t* __restrict__ Wvb,
    float* __restrict__ qf, float* __restrict__ kf, uint16_t* __restrict__ vt) {
  __shared__ __align__(16) uint16_t As[BM * BK];
  __shared__ __align__(16) uint16_t Bs[BN * BK];
  const int tid = threadIdx.x;
  const int m0 = blockIdx.y * BM;
  const int n0 = blockIdx.x * BN;

  const uint16_t* Wsrc; int nbase;
  if (n0 < 2048)      { Wsrc = Wqb; nbase = 0; }
  else if (n0 < 2560) { Wsrc = Wkb; nbase = 2048; }
  else                { Wsrc = Wvb; nbase = 2560; }

  const int lane = tid & 63, wave = tid >> 6;
  const int wm = (wave >> 1) * 64, wn = (wave & 1) * 64;
  const int quad = lane >> 4, r16 = lane & 15;
  const uint16_t* Abase = Xb + (size_t)m0 * D_;
  const uint16_t* Bbase = Wsrc + (size_t)(n0 - nbase) * D_;

  floatx4 acc[4][4];
  #pragma unroll
  for (int i = 0; i < 4; i++)
    #pragma unroll
    for (int j = 0; j < 4; j++) acc[i][j] = (floatx4){0.f, 0.f, 0.f, 0.f};

  for (int k0 = 0; k0 < D_; k0 += BK) {
    __syncthreads();
    stage_tile(Abase, As, k0, wave, lane);
    stage_tile(Bbase, Bs, k0, wave, lane);
    __syncthreads();  // drains vmcnt(0): async LDS writes complete
    bf16x8 af[4], bfr[4];
    #pragma unroll
    for (int i = 0; i < 4; i++)
      af[i] = *(const bf16x8*)&As[(wm + i * 16 + r16) * 32 + quad * 8];
    #pragma unroll
    for (int j = 0; j < 4; j++)
      bfr[j] = *(const bf16x8*)&Bs[(wn + j * 16 + r16) * 32 + quad * 8];
    #pragma unroll
    for (int i = 0; i < 4; i++)
      #pragma unroll
      for (int j = 0; j < 4; j++)
        acc[i][j] = mfma16(af[i], bfr[j], acc[i][j]);
  }

  // Epilogue scatter. D layout: row=quad*4+r, col=r16.
  // V is written TRANSPOSED: (b, kvh, d, t).
  #pragma unroll
  for (int i = 0; i < 4; i++) {
    #pragma unroll
    for (int j = 0; j < 4; j++) {
      #pragma unroll
      for (int r = 0; r < 4; r++) {
        int m = m0 + wm + i * 16 + quad * 4 + r;
        int n = n0 + wn + j * 16 + r16;
        float v = acc[i][j][r];
        int b = m >> 11, t = m & (T_ - 1);
        if (n < 2048) {
          int head = n >> 6, d = n & 63;
          qf[(((size_t)b * H_ + head) * T_ + t) * HD_ + d] = v;
        } else if (n < 2560) {
          int nl = n - 2048; int head = nl >> 6, d = nl & 63;
          kf[(((size_t)b * HKV_ + head) * T_ + t) * HD_ + d] = v;
        } else {
          int nl = n - 2560; int head = nl >> 6, d = nl & 63;
          vt[(((size_t)b * HKV_ + head) * HD_ + d) * T_ + t] = f2bf(v);
        }
      }
    }
  }
}

// ---------------- O projection GEMM: out = ao @ Wo^T ----------------------
__global__ __launch_bounds__(256) void oproj_gemm(
    const uint16_t* __restrict__ Ab, const uint16_t* __restrict__ Bb,
    float* __restrict__ C) {
  __shared__ __align__(16) uint16_t As[BM * BK];
  __shared__ __align__(16) uint16_t Bs[BN * BK];
  const int tid = threadIdx.x;
  const int m0 = blockIdx.y * BM;
  const int n0 = blockIdx.x * BN;
  const int lane = tid & 63, wave = tid >> 6;
  const int wm = (wave >> 1) * 64, wn = (wave & 1) * 64;
  const int quad = lane >> 4, r16 = lane & 15;
  const uint16_t* Abase = Ab + (size_t)m0 * D_;
  const uint16_t* Bbase = Bb + (size_t)n0 * D_;

  floatx4 acc[4][4];
  #pragma unroll
  for (int i = 0; i < 4; i++)
    #pragma unroll
    for (int j = 0; j < 4; j++) acc[i][j] = (floatx4){0.f, 0.f, 0.f, 0.f};

  for (int k0 = 0; k0 < D_; k0 += BK) {
    __syncthreads();
    stage_tile(Abase, As, k0, wave, lane);
    stage_tile(Bbase, Bs, k0, wave, lane);
    __syncthreads();
    bf16x8 af[4], bfr[4];
    #pragma unroll
    for (int i = 0; i < 4; i++)
      af[i] = *(const bf16x8*)&As[(wm + i * 16 + r16) * 32 + quad * 8];
    #pragma unroll
    for (int j = 0; j < 4; j++)
      bfr[j] = *(const bf16x8*)&Bs[(wn + j * 16 + r16) * 32 + quad * 8];
    #pragma unroll
    for (int i = 0; i < 4; i++)
      #pragma unroll
      for (int j = 0; j < 4; j++)
        acc[i][j] = mfma16(af[i], bfr[j], acc[i][j]);
  }
  #pragma unroll
  for (int i = 0; i < 4; i++)
    #pragma unroll
    for (int j = 0; j < 4; j++)
      #pragma unroll
      for (int r = 0; r < 4; r++) {
        int m = m0 + wm + i * 16 + quad * 4 + r;
        int n = n0 + wn + j * 16 + r16;
        C[(size_t)m * D_ + n] = acc[i][j][r];
      }
}

// ---------------- RMSNorm + RoPE (one wave per 64-elem head row) ----------
__global__ __launch_bounds__(256) void rmsrope(const float* __restrict__ src,
                                               uint16_t* __restrict__ dst,
                                               const float* __restrict__ w) {
  const int wave = threadIdx.x >> 6, lane = threadIdx.x & 63;
  const int rid = blockIdx.x * 4 + wave;
  const int t = rid & (T_ - 1);
  float v = src[(size_t)rid * HD_ + lane];
  float ss = v * v;
  #pragma unroll
  for (int off = 32; off; off >>= 1) ss += __shfl_xor(ss, off);
  float inv = rsqrtf(ss * (1.0f / HD_) + 1e-6f);
  float vn = v * inv * w[lane];
  int p = lane >> 1;
  float freq = exp2f((float)p * -0.0495300781f);  // 3^(-2p/64)
  float f = (float)t * freq;
  float s, c;
  sincosf(f, &s, &c);
  float other = __shfl_xor(vn, 1);
  float out = (lane & 1) ? (other * s + vn * c) : (vn * c - other * s);
  dst[(size_t)rid * HD_ + lane] = f2bf(out);
}

// ---------------- Flash attention v3 -------------------------------------
// Uniform work: each block processes q-tile (15-bx) then (bx) -> 34 k-iters
// for every block; grid (8,32,2)=512 blocks, steady 2 blocks/CU.
// PAD=68 (34 dwords): 4-way bank conflict on b128 reads (was 8-way at 72).
// Static-max softmax (|s|*SCALE <= 8 by Cauchy-Schwarz on RMS-normed q,k).
#define AT_PAD 68
#define LOG2E 1.44269504089f

__global__ __launch_bounds__(256) void attn(const uint16_t* __restrict__ qb,
                                            const uint16_t* __restrict__ kb,
                                            const uint16_t* __restrict__ vtb,
                                            uint16_t* __restrict__ ao) {
  const int tid = threadIdx.x;
  const int wave = tid >> 6, lane = tid & 63;
  const int quad = lane >> 4, r16 = lane & 15;
  const int h = blockIdx.y, b = blockIdx.z;
  const int kvh = h >> 2;

  const uint16_t* Q  = qb  + ((size_t)b * H_ + h) * T_ * HD_;
  const uint16_t* K  = kb  + ((size_t)b * HKV_ + kvh) * T_ * HD_;
  const uint16_t* Vt = vtb + ((size_t)b * HKV_ + kvh) * (size_t)HD_ * T_;

  __shared__ __align__(16) uint16_t Kl[64 * AT_PAD];
  __shared__ __align__(16) uint16_t Vl[64 * AT_PAD];
  __shared__ __align__(16) uint16_t Pl[4][32 * AT_PAD];
  uint16_t* myP = Pl[wave];

  const int srow = tid >> 2, sseg = tid & 3;

  for (int pass = 0; pass < 2; pass++) {
    const int qt = pass ? (int)blockIdx.x : 15 - (int)blockIdx.x;
    const int q0 = qt * 128;
    const int Rw = q0 + wave * 32;

    bf16x8 aq[2][2];
    #pragma unroll
    for (int m = 0; m < 2; m++)
      #pragma unroll
      for (int hh = 0; hh < 2; hh++)
        aq[m][hh] = *(const bf16x8*)(Q + (size_t)(Rw + m * 16 + r16) * HD_ + hh * 32 + quad * 8);

    floatx4 o[2][4];
    float l[2][4];
    #pragma unroll
    for (int m = 0; m < 2; m++) {
      #pragma unroll
      for (int j = 0; j < 4; j++) o[m][j] = (floatx4){0.f, 0.f, 0.f, 0.f};
      #pragma unroll
      for (int r = 0; r < 4; r++) l[m][r] = 0.f;
    }

    const int wkend = Rw + 31;
    const int iters = 2 * qt + 2;

    for (int it = 0; it < iters; it++) {
      const int kt = it * 64;
      {
        const uint16_t* kg = K + (size_t)(kt + srow) * HD_ + sseg * 16;
        uint4 k0 = *(const uint4*)kg;
        uint4 k1 = *(const uint4*)(kg + 8);
        const uint16_t* vg = Vt + (size_t)srow * T_ + kt + sseg * 16;
        uint4 v0 = *(const uint4*)vg;
        uint4 v1 = *(const uint4*)(vg + 8);
        __syncthreads();  // prior consumers done before overwrite
        *(uint4*)&Kl[srow * AT_PAD + sseg * 16] = k0;
        *(uint4*)&Kl[srow * AT_PAD + sseg * 16 + 8] = k1;
        *(uint4*)&Vl[srow * AT_PAD + sseg * 16] = v0;
        *(uint4*)&Vl[srow * AT_PAD + sseg * 16 + 8] = v1;
        __syncthreads();
      }
      if (kt > wkend) continue;  // wave past causal range (barriers already hit)

      const bool need_mask = (kt + 63) > Rw;

      floatx4 s[2][4];
      #pragma unroll
      for (int m = 0; m < 2; m++)
        #pragma unroll
        for (int nc = 0; nc < 4; nc++) s[m][nc] = (floatx4){0.f, 0.f, 0.f, 0.f};
      #pragma unroll
      for (int nc = 0; nc < 4; nc++) {
        bf16x8 kf0 = *(const bf16x8*)&Kl[(nc * 16 + r16) * AT_PAD + quad * 8];
        bf16x8 kf1 = *(const bf16x8*)&Kl[(nc * 16 + r16) * AT_PAD + 32 + quad * 8];
        #pragma unroll
        for (int m = 0; m < 2; m++) {
          s[m][nc] = mfma16(aq[m][0], kf0, s[m][nc]);
          s[m][nc] = mfma16(aq[m][1], kf1, s[m][nc]);
        }
      }

      // p = exp2(s*SCALE*log2e - 8*log2e); mask only in diagonal tiles
      #pragma unroll
      for (int m = 0; m < 2; m++) {
        #pragma unroll
        for (int nc = 0; nc < 4; nc++) {
          float pv[4];
          #pragma unroll
          for (int r = 0; r < 4; r++) {
            pv[r] = fast_exp2(fmaf(s[m][nc][r], SCALE_ * LOG2E, -8.0f * LOG2E));
            if (need_mask) {
              int col = kt + nc * 16 + r16;
              int rowq = Rw + m * 16 + quad * 4 + r;
              if (col > rowq) pv[r] = 0.f;
            }
            l[m][r] += pv[r];
          }
          int base = m * 16 + quad * 4;
          int cc = nc * 16 + r16;
          uint32_t u01 = f2bf_pk(pv[0], pv[1]);
          uint32_t u23 = f2bf_pk(pv[2], pv[3]);
          myP[(base + 0) * AT_PAD + cc] = (uint16_t)u01;
          myP[(base + 1) * AT_PAD + cc] = (uint16_t)(u01 >> 16);
          myP[(base + 2) * AT_PAD + cc] = (uint16_t)u23;
          myP[(base + 3) * AT_PAD + cc] = (uint16_t)(u23 >> 16);
        }
      }
      __asm__ __volatile__("s_waitcnt lgkmcnt(0)" ::: "memory");

      bf16x8 ap[2][2];
      #pragma unroll
      for (int m = 0; m < 2; m++) {
        ap[m][0] = *(const bf16x8*)&myP[(m * 16 + r16) * AT_PAD + quad * 8];
        ap[m][1] = *(const bf16x8*)&myP[(m * 16 + r16) * AT_PAD + 32 + quad * 8];
      }
      #pragma unroll
      for (int jn = 0; jn < 4; jn++) {
        bf16x8 vf0 = *(const bf16x8*)&Vl[(jn * 16 + r16) * AT_PAD + quad * 8];
        bf16x8 vf1 = *(const bf16x8*)&Vl[(jn * 16 + r16) * AT_PAD + 32 + quad * 8];
        #pragma unroll
        for (int m = 0; m < 2; m++) {
          o[m][jn] = mfma16(ap[m][0], vf0, o[m][jn]);
          o[m][jn] = mfma16(ap[m][1], vf1, o[m][jn]);
        }
      }
    }

    // final l reduction across 16 n-lanes, normalize, store
    #pragma unroll
    for (int m = 0; m < 2; m++)
      #pragma unroll
      for (int r = 0; r < 4; r++) {
        #pragma unroll
        for (int off = 8; off; off >>= 1) l[m][r] += __shfl_xor(l[m][r], off);
      }
    #pragma unroll
    for (int m = 0; m < 2; m++)
      #pragma unroll
      for (int jn = 0; jn < 4; jn++) {
        float inv0 = 1.0f / l[m][0], inv1 = 1.0f / l[m][1];
        float inv2 = 1.0f / l[m][2], inv3 = 1.0f / l[m][3];
        uint32_t u01 = f2bf_pk(o[m][jn][0] * inv0, o[m][jn][1] * inv1);
        uint32_t u23 = f2bf_pk(o[m][jn][2] * inv2, o[m][jn][3] * inv3);
        int t0 = Rw + m * 16 + quad * 4;
        size_t base = ((size_t)b * T_ + t0) * (H_ * HD_) + h * HD_ + jn * 16 + r16;
        ao[base]               = (uint16_t)u01;
        ao[base + 1 * H_ * HD_] = (uint16_t)(u01 >> 16);
        ao[base + 2 * H_ * HD_] = (uint16_t)u23;
        ao[base + 3 * H_ * HD_] = (uint16_t)(u23 >> 16);
      }
  }
}

extern "C" void kernel_launch(void* const* d_in, const int* in_sizes, int n_in,
                              void* d_out, int out_size, void* d_ws, size_t ws_size,
                              hipStream_t stream) {
  const float* x  = (const float*)d_in[0];
  const float* Wq = (const float*)d_in[1];
  const float* Wk = (const float*)d_in[2];
  const float* Wv = (const float*)d_in[3];
  const float* Wo = (const float*)d_in[4];
  const float* qw = (const float*)d_in[5];
  const float* kw = (const float*)d_in[6];
  float* out = (float*)d_out;

  char* ws = (char*)d_ws;
  uint16_t* xb  = (uint16_t*)(ws);               // 16 MB  x bf16 (later: ao bf16)
  uint16_t* wqb = (uint16_t*)(ws + 16777216);    // 8 MB
  uint16_t* wkb = (uint16_t*)(ws + 25165824);    // 2 MB
  uint16_t* wvb = (uint16_t*)(ws + 27262976);    // 2 MB
  uint16_t* wob = (uint16_t*)(ws + 29360128);    // 8 MB
  float*    qf  = (float*)   (ws + 37748736);    // 32 MB  q fp32 (b,h,t,d)
  float*    kf  = (float*)   (ws + 71303168);    // 8 MB   k fp32 (b,kvh,t,d)
  uint16_t* qbf = (uint16_t*)(ws + 79691776);    // 16 MB  q bf16 post norm+rope
  uint16_t* kbf = (uint16_t*)(ws + 96468992);    // 4 MB
  uint16_t* vtb = (uint16_t*)(ws + 100663296);   // 4 MB   V^T bf16 (b,kvh,d,t)
  uint16_t* aob = xb;

  cvt_all<<<18432, 256, 0, stream>>>(x, Wq, Wk, Wv, Wo, xb, wqb, wkb, wvb, wob);

  qkv_gemm<<<dim3(24, 32), 256, 0, stream>>>(xb, wqb, wkb, wvb, qf, kf, vtb);

  rmsrope<<<32768, 256, 0, stream>>>(qf, qbf, qw);
  rmsrope<<<8192, 256, 0, stream>>>(kf, kbf, kw);

  attn<<<dim3(8, 32, 2), 256, 0, stream>>>(qbf, kbf, vtb, aob);

  oproj_gemm<<<dim3(16, 32), 256, 0, stream>>>(aob, wob, out);
}

// Round 4
// 357.626 us; speedup vs baseline: 1.9026x; 1.1747x over previous
//
#include <hip/hip_runtime.h>
#include <hip/hip_bf16.h>
#include <stdint.h>

// Problem constants
#define B_ 2
#define T_ 2048
#define D_ 2048
#define H_ 32
#define HKV_ 8
#define HD_ 64
#define SCALE_ 0.125f  // HD^-0.5

typedef float floatx4 __attribute__((ext_vector_type(4)));
typedef __bf16 bf16x8 __attribute__((ext_vector_type(8)));

__device__ inline floatx4 mfma16(bf16x8 a, bf16x8 b, floatx4 c) {
  return __builtin_amdgcn_mfma_f32_16x16x32_bf16(a, b, c, 0, 0, 0);
}

// RNE float -> bf16 bits
__device__ inline uint16_t f2bf(float f) {
  union { float f; uint32_t u; } x; x.f = f;
  uint32_t r = x.u + 0x7fffu + ((x.u >> 16) & 1u);
  return (uint16_t)(r >> 16);
}

__device__ inline uint32_t f2bf_pk(float a, float b) {
#if __has_builtin(__builtin_amdgcn_cvt_pk_bf16_f32)
  auto pk = __builtin_amdgcn_cvt_pk_bf16_f32(a, b);
  return __builtin_bit_cast(uint32_t, pk);
#else
  return (uint32_t)f2bf(a) | ((uint32_t)f2bf(b) << 16);
#endif
}

__device__ inline float fast_exp2(float x) {
#if __has_builtin(__builtin_amdgcn_exp2f)
  return __builtin_amdgcn_exp2f(x);
#else
  return __expf(x * 0.69314718056f);
#endif
}

#if __has_builtin(__builtin_amdgcn_global_load_lds)
#define HAVE_ASYNC_LDS 1
typedef const __attribute__((address_space(1))) uint32_t* gas1_u32;
typedef __attribute__((address_space(3))) uint32_t* las3_u32;
__device__ inline void g2lds16(const uint16_t* g, uint16_t* l) {
  __builtin_amdgcn_global_load_lds((gas1_u32)(const void*)g, (las3_u32)(void*)l, 16, 0, 0);
}
#endif

// ---------------- merged fp32 -> bf16 convert (4 elems/thread) ------------
__global__ __launch_bounds__(256) void cvt_all(
    const float* __restrict__ x, const float* __restrict__ wq,
    const float* __restrict__ wk, const float* __restrict__ wv,
    const float* __restrict__ wo,
    uint16_t* __restrict__ xb, uint16_t* __restrict__ wqb,
    uint16_t* __restrict__ wkb, uint16_t* __restrict__ wvb,
    uint16_t* __restrict__ wob) {
  int i = blockIdx.x * 256 + threadIdx.x;
  const float* src; uint16_t* dst; int off;
  if (i < 2097152)      { src = x;  dst = xb;  off = i; }
  else if (i < 3145728) { src = wq; dst = wqb; off = i - 2097152; }
  else if (i < 3407872) { src = wk; dst = wkb; off = i - 3145728; }
  else if (i < 3670016) { src = wv; dst = wvb; off = i - 3407872; }
  else                  { src = wo; dst = wob; off = i - 3670016; }
  float4 v = ((const float4*)src)[off];
  uint64_t packed = (uint64_t)f2bf_pk(v.x, v.y) | ((uint64_t)f2bf_pk(v.z, v.w) << 32);
  ((uint64_t*)dst)[off] = packed;
}

// ---------------- GEMM common: swizzled BK=64 staging ----------------
// Tile 128 rows x 64 cols bf16, row stride 64 elems (128 B), no padding.
// XOR swizzle: element (row, cg) lives at physical col-group cg^(row&7)
// (cg = 8-elem/16B group). Staging keeps the wave-uniform-base + lane*16B
// contract of global_load_lds (lane's GLOBAL address carries the swizzle);
// fragment reads then hit all 32 banks at 2 lanes/bank (free, m136).
#define BM 128
#define BN 128
#define BK 64

__device__ inline void stage64(const uint16_t* gbase, uint16_t* lds,
                               int k0, int wave, int lane) {
#ifdef HAVE_ASYNC_LDS
  #pragma unroll
  for (int c = 0; c < 4; c++) {
    int chunk = wave * 4 + c;
    int row = chunk * 8 + (lane >> 3);
    int cg  = (lane & 7) ^ ((lane >> 3) & 7);
    g2lds16(gbase + (size_t)row * D_ + k0 + cg * 8, lds + chunk * 512 + lane * 8);
  }
#else
  #pragma unroll
  for (int c = 0; c < 4; c++) {
    int chunk = wave * 4 + c;
    int row = chunk * 8 + (lane >> 3);
    int cg  = (lane & 7) ^ ((lane >> 3) & 7);
    *(uint4*)&lds[chunk * 512 + lane * 8] =
        *(const uint4*)(gbase + (size_t)row * D_ + k0 + cg * 8);
  }
#endif
}

__device__ inline bf16x8 frag64(const uint16_t* lds, int row, int cg) {
  int pcg = cg ^ (row & 7);
  return *(const bf16x8*)&lds[row * 64 + pcg * 8];
}

// K-loop shared by both GEMMs: 32 iters, 32 MFMA / 16 ds_read_b128 / 8 g2lds per iter.
#define GEMM_KLOOP(Abase, Bbase)                                          \
  for (int k0 = 0; k0 < D_; k0 += BK) {                                   \
    __syncthreads();                                                      \
    stage64(Abase, As, k0, wave, lane);                                   \
    stage64(Bbase, Bs, k0, wave, lane);                                   \
    __syncthreads();                                                      \
    bf16x8 af[4][2], bfr[4][2];                                           \
    _Pragma("unroll")                                                     \
    for (int i = 0; i < 4; i++) {                                         \
      af[i][0] = frag64(As, wm + i * 16 + r16, quad);                     \
      af[i][1] = frag64(As, wm + i * 16 + r16, 4 + quad);                 \
    }                                                                     \
    _Pragma("unroll")                                                     \
    for (int j = 0; j < 4; j++) {                                         \
      bfr[j][0] = frag64(Bs, wn + j * 16 + r16, quad);                    \
      bfr[j][1] = frag64(Bs, wn + j * 16 + r16, 4 + quad);                \
    }                                                                     \
    _Pragma("unroll")                                                     \
    for (int i = 0; i < 4; i++)                                           \
      _Pragma("unroll")                                                   \
      for (int j = 0; j < 4; j++) {                                       \
        acc[i][j] = mfma16(af[i][0], bfr[j][0], acc[i][j]);               \
        acc[i][j] = mfma16(af[i][1], bfr[j][1], acc[i][j]);               \
      }                                                                   \
  }

// ---------------- fused QKV projection + RMSNorm + RoPE -------------------
// n-tiles: 0..15 Q | 16..19 K | 20..23 V. Each wave's 64-col range = 1 head.
__global__ __launch_bounds__(256) void qkv_gemm(
    const uint16_t* __restrict__ Xb, const uint16_t* __restrict__ Wqb,
    const uint16_t* __restrict__ Wkb, const uint16_t* __restrict__ Wvb,
    const float* __restrict__ qnw, const float* __restrict__ knw,
    uint16_t* __restrict__ qbf, uint16_t* __restrict__ kbf,
    uint16_t* __restrict__ vt) {
  __shared__ __align__(16) uint16_t As[BM * BK];
  __shared__ __align__(16) uint16_t Bs[BN * BK];
  const int tid = threadIdx.x;
  const int m0 = blockIdx.y * BM;
  const int n0 = blockIdx.x * BN;

  const uint16_t* Wsrc; int nbase;
  if (n0 < 2048)      { Wsrc = Wqb; nbase = 0; }
  else if (n0 < 2560) { Wsrc = Wkb; nbase = 2048; }
  else                { Wsrc = Wvb; nbase = 2560; }

  const int lane = tid & 63, wave = tid >> 6;
  const int wm = (wave >> 1) * 64, wn = (wave & 1) * 64;
  const int quad = lane >> 4, r16 = lane & 15;
  const uint16_t* Abase = Xb + (size_t)m0 * D_;
  const uint16_t* Bbase = Wsrc + (size_t)(n0 - nbase) * D_;

  floatx4 acc[4][4];
  #pragma unroll
  for (int i = 0; i < 4; i++)
    #pragma unroll
    for (int j = 0; j < 4; j++) acc[i][j] = (floatx4){0.f, 0.f, 0.f, 0.f};

  GEMM_KLOOP(Abase, Bbase)

  // ---- Epilogue ----
  if (n0 < 2560) {
    // Q or K: RMSNorm over the 64-col head dim + RoPE, store bf16.
    const int isK = (n0 >= 2048);
    const float* nw = isK ? knw : qnw;
    const int head = (n0 - (isK ? 2048 : 0) + wn) >> 6;
    uint16_t* dst = isK ? kbf : qbf;
    const int NH = isK ? HKV_ : H_;
    float wreg[4];
    #pragma unroll
    for (int j = 0; j < 4; j++) wreg[j] = nw[j * 16 + r16];
    float freq[4];
    #pragma unroll
    for (int j = 0; j < 4; j++)
      freq[j] = exp2f((float)(j * 8 + (r16 >> 1)) * -0.0495300781f);  // 3^(-2p/64)
    #pragma unroll
    for (int i = 0; i < 4; i++) {
      #pragma unroll
      for (int r = 0; r < 4; r++) {
        float ss = 0.f;
        #pragma unroll
        for (int j = 0; j < 4; j++) ss += acc[i][j][r] * acc[i][j][r];
        #pragma unroll
        for (int off = 8; off; off >>= 1) ss += __shfl_xor(ss, off);
        float inv = rsqrtf(ss * (1.0f / HD_) + 1e-6f);
        int m = m0 + wm + i * 16 + quad * 4 + r;
        int b = m >> 11, t = m & (T_ - 1);
        size_t rowbase = (((size_t)b * NH + head) * T_ + t) * HD_;
        #pragma unroll
        for (int j = 0; j < 4; j++) {
          float vn = acc[i][j][r] * inv * wreg[j];
          float other = __shfl_xor(vn, 1);
          float f = (float)t * freq[j];
          float s, c;
          __sincosf(f, &s, &c);
          float outv = (r16 & 1) ? (other * s + vn * c) : (vn * c - other * s);
          dst[rowbase + j * 16 + r16] = f2bf(outv);
        }
      }
    }
  } else {
    // V: store transposed (b, kvh, d, t)
    #pragma unroll
    for (int i = 0; i < 4; i++)
      #pragma unroll
      for (int j = 0; j < 4; j++)
        #pragma unroll
        for (int r = 0; r < 4; r++) {
          int m = m0 + wm + i * 16 + quad * 4 + r;
          int n = n0 + wn + j * 16 + r16 - 2560;
          int b = m >> 11, t = m & (T_ - 1);
          int head = n >> 6, d = n & 63;
          vt[(((size_t)b * HKV_ + head) * HD_ + d) * T_ + t] = f2bf(acc[i][j][r]);
        }
  }
}

// ---------------- O projection GEMM: out = ao @ Wo^T ----------------------
__global__ __launch_bounds__(256) void oproj_gemm(
    const uint16_t* __restrict__ Ab, const uint16_t* __restrict__ Bb,
    float* __restrict__ C) {
  __shared__ __align__(16) uint16_t As[BM * BK];
  __shared__ __align__(16) uint16_t Bs[BN * BK];
  const int tid = threadIdx.x;
  const int m0 = blockIdx.y * BM;
  const int n0 = blockIdx.x * BN;
  const int lane = tid & 63, wave = tid >> 6;
  const int wm = (wave >> 1) * 64, wn = (wave & 1) * 64;
  const int quad = lane >> 4, r16 = lane & 15;
  const uint16_t* Abase = Ab + (size_t)m0 * D_;
  const uint16_t* Bbase = Bb + (size_t)n0 * D_;

  floatx4 acc[4][4];
  #pragma unroll
  for (int i = 0; i < 4; i++)
    #pragma unroll
    for (int j = 0; j < 4; j++) acc[i][j] = (floatx4){0.f, 0.f, 0.f, 0.f};

  GEMM_KLOOP(Abase, Bbase)

  #pragma unroll
  for (int i = 0; i < 4; i++)
    #pragma unroll
    for (int j = 0; j < 4; j++)
      #pragma unroll
      for (int r = 0; r < 4; r++) {
        int m = m0 + wm + i * 16 + quad * 4 + r;
        int n = n0 + wn + j * 16 + r16;
        C[(size_t)m * D_ + n] = acc[i][j][r];
      }
}

// ---------------- Flash attention (unchanged from round 3) ----------------
#define AT_PAD 68
#define LOG2E 1.44269504089f

__global__ __launch_bounds__(256) void attn(const uint16_t* __restrict__ qb,
                                            const uint16_t* __restrict__ kb,
                                            const uint16_t* __restrict__ vtb,
                                            uint16_t* __restrict__ ao) {
  const int tid = threadIdx.x;
  const int wave = tid >> 6, lane = tid & 63;
  const int quad = lane >> 4, r16 = lane & 15;
  const int h = blockIdx.y, b = blockIdx.z;
  const int kvh = h >> 2;

  const uint16_t* Q  = qb  + ((size_t)b * H_ + h) * T_ * HD_;
  const uint16_t* K  = kb  + ((size_t)b * HKV_ + kvh) * T_ * HD_;
  const uint16_t* Vt = vtb + ((size_t)b * HKV_ + kvh) * (size_t)HD_ * T_;

  __shared__ __align__(16) uint16_t Kl[64 * AT_PAD];
  __shared__ __align__(16) uint16_t Vl[64 * AT_PAD];
  __shared__ __align__(16) uint16_t Pl[4][32 * AT_PAD];
  uint16_t* myP = Pl[wave];

  const int srow = tid >> 2, sseg = tid & 3;

  for (int pass = 0; pass < 2; pass++) {
    const int qt = pass ? (int)blockIdx.x : 15 - (int)blockIdx.x;
    const int q0 = qt * 128;
    const int Rw = q0 + wave * 32;

    bf16x8 aq[2][2];
    #pragma unroll
    for (int m = 0; m < 2; m++)
      #pragma unroll
      for (int hh = 0; hh < 2; hh++)
        aq[m][hh] = *(const bf16x8*)(Q + (size_t)(Rw + m * 16 + r16) * HD_ + hh * 32 + quad * 8);

    floatx4 o[2][4];
    float l[2][4];
    #pragma unroll
    for (int m = 0; m < 2; m++) {
      #pragma unroll
      for (int j = 0; j < 4; j++) o[m][j] = (floatx4){0.f, 0.f, 0.f, 0.f};
      #pragma unroll
      for (int r = 0; r < 4; r++) l[m][r] = 0.f;
    }

    const int wkend = Rw + 31;
    const int iters = 2 * qt + 2;

    for (int it = 0; it < iters; it++) {
      const int kt = it * 64;
      {
        const uint16_t* kg = K + (size_t)(kt + srow) * HD_ + sseg * 16;
        uint4 k0 = *(const uint4*)kg;
        uint4 k1 = *(const uint4*)(kg + 8);
        const uint16_t* vg = Vt + (size_t)srow * T_ + kt + sseg * 16;
        uint4 v0 = *(const uint4*)vg;
        uint4 v1 = *(const uint4*)(vg + 8);
        __syncthreads();
        *(uint4*)&Kl[srow * AT_PAD + sseg * 16] = k0;
        *(uint4*)&Kl[srow * AT_PAD + sseg * 16 + 8] = k1;
        *(uint4*)&Vl[srow * AT_PAD + sseg * 16] = v0;
        *(uint4*)&Vl[srow * AT_PAD + sseg * 16 + 8] = v1;
        __syncthreads();
      }
      if (kt > wkend) continue;

      const bool need_mask = (kt + 63) > Rw;

      floatx4 s[2][4];
      #pragma unroll
      for (int m = 0; m < 2; m++)
        #pragma unroll
        for (int nc = 0; nc < 4; nc++) s[m][nc] = (floatx4){0.f, 0.f, 0.f, 0.f};
      #pragma unroll
      for (int nc = 0; nc < 4; nc++) {
        bf16x8 kf0 = *(const bf16x8*)&Kl[(nc * 16 + r16) * AT_PAD + quad * 8];
        bf16x8 kf1 = *(const bf16x8*)&Kl[(nc * 16 + r16) * AT_PAD + 32 + quad * 8];
        #pragma unroll
        for (int m = 0; m < 2; m++) {
          s[m][nc] = mfma16(aq[m][0], kf0, s[m][nc]);
          s[m][nc] = mfma16(aq[m][1], kf1, s[m][nc]);
        }
      }

      #pragma unroll
      for (int m = 0; m < 2; m++) {
        #pragma unroll
        for (int nc = 0; nc < 4; nc++) {
          float pv[4];
          #pragma unroll
          for (int r = 0; r < 4; r++) {
            pv[r] = fast_exp2(fmaf(s[m][nc][r], SCALE_ * LOG2E, -8.0f * LOG2E));
            if (need_mask) {
              int col = kt + nc * 16 + r16;
              int rowq = Rw + m * 16 + quad * 4 + r;
              if (col > rowq) pv[r] = 0.f;
            }
            l[m][r] += pv[r];
          }
          int base = m * 16 + quad * 4;
          int cc = nc * 16 + r16;
          uint32_t u01 = f2bf_pk(pv[0], pv[1]);
          uint32_t u23 = f2bf_pk(pv[2], pv[3]);
          myP[(base + 0) * AT_PAD + cc] = (uint16_t)u01;
          myP[(base + 1) * AT_PAD + cc] = (uint16_t)(u01 >> 16);
          myP[(base + 2) * AT_PAD + cc] = (uint16_t)u23;
          myP[(base + 3) * AT_PAD + cc] = (uint16_t)(u23 >> 16);
        }
      }
      __asm__ __volatile__("s_waitcnt lgkmcnt(0)" ::: "memory");

      bf16x8 ap[2][2];
      #pragma unroll
      for (int m = 0; m < 2; m++) {
        ap[m][0] = *(const bf16x8*)&myP[(m * 16 + r16) * AT_PAD + quad * 8];
        ap[m][1] = *(const bf16x8*)&myP[(m * 16 + r16) * AT_PAD + 32 + quad * 8];
      }
      #pragma unroll
      for (int jn = 0; jn < 4; jn++) {
        bf16x8 vf0 = *(const bf16x8*)&Vl[(jn * 16 + r16) * AT_PAD + quad * 8];
        bf16x8 vf1 = *(const bf16x8*)&Vl[(jn * 16 + r16) * AT_PAD + 32 + quad * 8];
        #pragma unroll
        for (int m = 0; m < 2; m++) {
          o[m][jn] = mfma16(ap[m][0], vf0, o[m][jn]);
          o[m][jn] = mfma16(ap[m][1], vf1, o[m][jn]);
        }
      }
    }

    #pragma unroll
    for (int m = 0; m < 2; m++)
      #pragma unroll
      for (int r = 0; r < 4; r++) {
        #pragma unroll
        for (int off = 8; off; off >>= 1) l[m][r] += __shfl_xor(l[m][r], off);
      }
    #pragma unroll
    for (int m = 0; m < 2; m++)
      #pragma unroll
      for (int jn = 0; jn < 4; jn++) {
        float inv0 = 1.0f / l[m][0], inv1 = 1.0f / l[m][1];
        float inv2 = 1.0f / l[m][2], inv3 = 1.0f / l[m][3];
        uint32_t u01 = f2bf_pk(o[m][jn][0] * inv0, o[m][jn][1] * inv1);
        uint32_t u23 = f2bf_pk(o[m][jn][2] * inv2, o[m][jn][3] * inv3);
        int t0 = Rw + m * 16 + quad * 4;
        size_t base = ((size_t)b * T_ + t0) * (H_ * HD_) + h * HD_ + jn * 16 + r16;
        ao[base]                = (uint16_t)u01;
        ao[base + 1 * H_ * HD_] = (uint16_t)(u01 >> 16);
        ao[base + 2 * H_ * HD_] = (uint16_t)u23;
        ao[base + 3 * H_ * HD_] = (uint16_t)(u23 >> 16);
      }
  }
}

extern "C" void kernel_launch(void* const* d_in, const int* in_sizes, int n_in,
                              void* d_out, int out_size, void* d_ws, size_t ws_size,
                              hipStream_t stream) {
  const float* x  = (const float*)d_in[0];
  const float* Wq = (const float*)d_in[1];
  const float* Wk = (const float*)d_in[2];
  const float* Wv = (const float*)d_in[3];
  const float* Wo = (const float*)d_in[4];
  const float* qw = (const float*)d_in[5];
  const float* kw = (const float*)d_in[6];
  float* out = (float*)d_out;

  char* ws = (char*)d_ws;
  uint16_t* xb  = (uint16_t*)(ws);               // 16 MB  x bf16 (later: ao bf16)
  uint16_t* wqb = (uint16_t*)(ws + 16777216);    // 8 MB
  uint16_t* wkb = (uint16_t*)(ws + 25165824);    // 2 MB
  uint16_t* wvb = (uint16_t*)(ws + 27262976);    // 2 MB
  uint16_t* wob = (uint16_t*)(ws + 29360128);    // 8 MB
  uint16_t* qbf = (uint16_t*)(ws + 37748736);    // 16 MB  q bf16 (b,h,t,d) post norm+rope
  uint16_t* kbf = (uint16_t*)(ws + 54525952);    // 4 MB   k bf16 (b,kvh,t,d)
  uint16_t* vtb = (uint16_t*)(ws + 58720256);    // 4 MB   V^T bf16 (b,kvh,d,t)
  uint16_t* aob = xb;

  cvt_all<<<18432, 256, 0, stream>>>(x, Wq, Wk, Wv, Wo, xb, wqb, wkb, wvb, wob);

  qkv_gemm<<<dim3(24, 32), 256, 0, stream>>>(xb, wqb, wkb, wvb, qw, kw, qbf, kbf, vtb);

  attn<<<dim3(8, 32, 2), 256, 0, stream>>>(qbf, kbf, vtb, aob);

  oproj_gemm<<<dim3(16, 32), 256, 0, stream>>>(aob, wob, out);
}

// Round 5
// 339.680 us; speedup vs baseline: 2.0032x; 1.0528x over previous
//
#include <hip/hip_runtime.h>
#include <hip/hip_bf16.h>
#include <stdint.h>

// Problem constants
#define B_ 2
#define T_ 2048
#define D_ 2048
#define H_ 32
#define HKV_ 8
#define HD_ 64
#define SCALE_ 0.125f  // HD^-0.5

typedef float floatx4 __attribute__((ext_vector_type(4)));
typedef __bf16 bf16x8 __attribute__((ext_vector_type(8)));
typedef __bf16 bf16x4 __attribute__((ext_vector_type(4)));
typedef short short4v __attribute__((ext_vector_type(4)));

__device__ inline floatx4 mfma16(bf16x8 a, bf16x8 b, floatx4 c) {
  return __builtin_amdgcn_mfma_f32_16x16x32_bf16(a, b, c, 0, 0, 0);
}

// 16x16x16 bf16 MFMA: A/B = 4 bf16/lane [m=lane&15][k=quad*4+j]; C/D same as x32.
__device__ inline floatx4 mfma16k16(bf16x4 a, bf16x4 b, floatx4 c) {
#if __has_builtin(__builtin_amdgcn_mfma_f32_16x16x16_bf16)
  return __builtin_amdgcn_mfma_f32_16x16x16_bf16(a, b, c, 0, 0, 0);
#else
  return __builtin_amdgcn_mfma_f32_16x16x16bf16_1k(
      __builtin_bit_cast(short4v, a), __builtin_bit_cast(short4v, b), c, 0, 0, 0);
#endif
}

// RNE float -> bf16 bits
__device__ inline uint16_t f2bf(float f) {
  union { float f; uint32_t u; } x; x.f = f;
  uint32_t r = x.u + 0x7fffu + ((x.u >> 16) & 1u);
  return (uint16_t)(r >> 16);
}

__device__ inline uint32_t f2bf_pk(float a, float b) {
#if __has_builtin(__builtin_amdgcn_cvt_pk_bf16_f32)
  auto pk = __builtin_amdgcn_cvt_pk_bf16_f32(a, b);
  return __builtin_bit_cast(uint32_t, pk);
#else
  return (uint32_t)f2bf(a) | ((uint32_t)f2bf(b) << 16);
#endif
}

__device__ inline float fast_exp2(float x) {
#if __has_builtin(__builtin_amdgcn_exp2f)
  return __builtin_amdgcn_exp2f(x);
#else
  return __expf(x * 0.69314718056f);
#endif
}

#if __has_builtin(__builtin_amdgcn_global_load_lds)
#define HAVE_ASYNC_LDS 1
typedef const __attribute__((address_space(1))) uint32_t* gas1_u32;
typedef __attribute__((address_space(3))) uint32_t* las3_u32;
__device__ inline void g2lds16(const uint16_t* g, uint16_t* l) {
  __builtin_amdgcn_global_load_lds((gas1_u32)(const void*)g, (las3_u32)(void*)l, 16, 0, 0);
}
#endif

// ---------------- merged fp32 -> bf16 convert (4 elems/thread) ------------
__global__ __launch_bounds__(256) void cvt_all(
    const float* __restrict__ x, const float* __restrict__ wq,
    const float* __restrict__ wk, const float* __restrict__ wv,
    const float* __restrict__ wo,
    uint16_t* __restrict__ xb, uint16_t* __restrict__ wqb,
    uint16_t* __restrict__ wkb, uint16_t* __restrict__ wvb,
    uint16_t* __restrict__ wob) {
  int i = blockIdx.x * 256 + threadIdx.x;
  const float* src; uint16_t* dst; int off;
  if (i < 2097152)      { src = x;  dst = xb;  off = i; }
  else if (i < 3145728) { src = wq; dst = wqb; off = i - 2097152; }
  else if (i < 3407872) { src = wk; dst = wkb; off = i - 3145728; }
  else if (i < 3670016) { src = wv; dst = wvb; off = i - 3407872; }
  else                  { src = wo; dst = wob; off = i - 3670016; }
  float4 v = ((const float4*)src)[off];
  uint64_t packed = (uint64_t)f2bf_pk(v.x, v.y) | ((uint64_t)f2bf_pk(v.z, v.w) << 32);
  ((uint64_t*)dst)[off] = packed;
}

// ---------------- GEMM common: swizzled BK=64 staging ----------------
// Tile 128 rows x 64 cols bf16, row stride 64 elems, no padding.
// XOR swizzle: element (row, cg) at physical col-group cg^(row&7).
#define BM 128
#define BN 128
#define BK 64

__device__ inline void stage64(const uint16_t* gbase, uint16_t* lds,
                               int k0, int wave, int lane) {
#ifdef HAVE_ASYNC_LDS
  #pragma unroll
  for (int c = 0; c < 4; c++) {
    int chunk = wave * 4 + c;
    int row = chunk * 8 + (lane >> 3);
    int cg  = (lane & 7) ^ ((lane >> 3) & 7);
    g2lds16(gbase + (size_t)row * D_ + k0 + cg * 8, lds + chunk * 512 + lane * 8);
  }
#else
  #pragma unroll
  for (int c = 0; c < 4; c++) {
    int chunk = wave * 4 + c;
    int row = chunk * 8 + (lane >> 3);
    int cg  = (lane & 7) ^ ((lane >> 3) & 7);
    *(uint4*)&lds[chunk * 512 + lane * 8] =
        *(const uint4*)(gbase + (size_t)row * D_ + k0 + cg * 8);
  }
#endif
}

__device__ inline bf16x8 frag64(const uint16_t* lds, int row, int cg) {
  int pcg = cg ^ (row & 7);
  return *(const bf16x8*)&lds[row * 64 + pcg * 8];
}

#define GEMM_KLOOP(Abase, Bbase)                                          \
  for (int k0 = 0; k0 < D_; k0 += BK) {                                   \
    __syncthreads();                                                      \
    stage64(Abase, As, k0, wave, lane);                                   \
    stage64(Bbase, Bs, k0, wave, lane);                                   \
    __syncthreads();                                                      \
    bf16x8 af[4][2], bfr[4][2];                                           \
    _Pragma("unroll")                                                     \
    for (int i = 0; i < 4; i++) {                                         \
      af[i][0] = frag64(As, wm + i * 16 + r16, quad);                     \
      af[i][1] = frag64(As, wm + i * 16 + r16, 4 + quad);                 \
    }                                                                     \
    _Pragma("unroll")                                                     \
    for (int j = 0; j < 4; j++) {                                         \
      bfr[j][0] = frag64(Bs, wn + j * 16 + r16, quad);                    \
      bfr[j][1] = frag64(Bs, wn + j * 16 + r16, 4 + quad);                \
    }                                                                     \
    _Pragma("unroll")                                                     \
    for (int i = 0; i < 4; i++)                                           \
      _Pragma("unroll")                                                   \
      for (int j = 0; j < 4; j++) {                                       \
        acc[i][j] = mfma16(af[i][0], bfr[j][0], acc[i][j]);               \
        acc[i][j] = mfma16(af[i][1], bfr[j][1], acc[i][j]);               \
      }                                                                   \
  }

// ---------------- fused QKV projection + RMSNorm + RoPE -------------------
__global__ __launch_bounds__(256) void qkv_gemm(
    const uint16_t* __restrict__ Xb, const uint16_t* __restrict__ Wqb,
    const uint16_t* __restrict__ Wkb, const uint16_t* __restrict__ Wvb,
    const float* __restrict__ qnw, const float* __restrict__ knw,
    uint16_t* __restrict__ qbf, uint16_t* __restrict__ kbf,
    uint16_t* __restrict__ vt) {
  __shared__ __align__(16) uint16_t As[BM * BK];
  __shared__ __align__(16) uint16_t Bs[BN * BK];
  const int tid = threadIdx.x;
  const int m0 = blockIdx.y * BM;
  const int n0 = blockIdx.x * BN;

  const uint16_t* Wsrc; int nbase;
  if (n0 < 2048)      { Wsrc = Wqb; nbase = 0; }
  else if (n0 < 2560) { Wsrc = Wkb; nbase = 2048; }
  else                { Wsrc = Wvb; nbase = 2560; }

  const int lane = tid & 63, wave = tid >> 6;
  const int wm = (wave >> 1) * 64, wn = (wave & 1) * 64;
  const int quad = lane >> 4, r16 = lane & 15;
  const uint16_t* Abase = Xb + (size_t)m0 * D_;
  const uint16_t* Bbase = Wsrc + (size_t)(n0 - nbase) * D_;

  floatx4 acc[4][4];
  #pragma unroll
  for (int i = 0; i < 4; i++)
    #pragma unroll
    for (int j = 0; j < 4; j++) acc[i][j] = (floatx4){0.f, 0.f, 0.f, 0.f};

  GEMM_KLOOP(Abase, Bbase)

  if (n0 < 2560) {
    const int isK = (n0 >= 2048);
    const float* nw = isK ? knw : qnw;
    const int head = (n0 - (isK ? 2048 : 0) + wn) >> 6;
    uint16_t* dst = isK ? kbf : qbf;
    const int NH = isK ? HKV_ : H_;
    float wreg[4];
    #pragma unroll
    for (int j = 0; j < 4; j++) wreg[j] = nw[j * 16 + r16];
    float freq[4];
    #pragma unroll
    for (int j = 0; j < 4; j++)
      freq[j] = exp2f((float)(j * 8 + (r16 >> 1)) * -0.0495300781f);  // 3^(-2p/64)
    #pragma unroll
    for (int i = 0; i < 4; i++) {
      #pragma unroll
      for (int r = 0; r < 4; r++) {
        float ss = 0.f;
        #pragma unroll
        for (int j = 0; j < 4; j++) ss += acc[i][j][r] * acc[i][j][r];
        #pragma unroll
        for (int off = 8; off; off >>= 1) ss += __shfl_xor(ss, off);
        float inv = rsqrtf(ss * (1.0f / HD_) + 1e-6f);
        int m = m0 + wm + i * 16 + quad * 4 + r;
        int b = m >> 11, t = m & (T_ - 1);
        size_t rowbase = (((size_t)b * NH + head) * T_ + t) * HD_;
        #pragma unroll
        for (int j = 0; j < 4; j++) {
          float vn = acc[i][j][r] * inv * wreg[j];
          float other = __shfl_xor(vn, 1);
          float f = (float)t * freq[j];
          float s, c;
          __sincosf(f, &s, &c);
          float outv = (r16 & 1) ? (other * s + vn * c) : (vn * c - other * s);
          dst[rowbase + j * 16 + r16] = f2bf(outv);
        }
      }
    }
  } else {
    #pragma unroll
    for (int i = 0; i < 4; i++)
      #pragma unroll
      for (int j = 0; j < 4; j++)
        #pragma unroll
        for (int r = 0; r < 4; r++) {
          int m = m0 + wm + i * 16 + quad * 4 + r;
          int n = n0 + wn + j * 16 + r16 - 2560;
          int b = m >> 11, t = m & (T_ - 1);
          int head = n >> 6, d = n & 63;
          vt[(((size_t)b * HKV_ + head) * HD_ + d) * T_ + t] = f2bf(acc[i][j][r]);
        }
  }
}

// ---------------- O projection GEMM: out = ao @ Wo^T ----------------------
__global__ __launch_bounds__(256) void oproj_gemm(
    const uint16_t* __restrict__ Ab, const uint16_t* __restrict__ Bb,
    float* __restrict__ C) {
  __shared__ __align__(16) uint16_t As[BM * BK];
  __shared__ __align__(16) uint16_t Bs[BN * BK];
  const int tid = threadIdx.x;
  const int m0 = blockIdx.y * BM;
  const int n0 = blockIdx.x * BN;
  const int lane = tid & 63, wave = tid >> 6;
  const int wm = (wave >> 1) * 64, wn = (wave & 1) * 64;
  const int quad = lane >> 4, r16 = lane & 15;
  const uint16_t* Abase = Ab + (size_t)m0 * D_;
  const uint16_t* Bbase = Bb + (size_t)n0 * D_;

  floatx4 acc[4][4];
  #pragma unroll
  for (int i = 0; i < 4; i++)
    #pragma unroll
    for (int j = 0; j < 4; j++) acc[i][j] = (floatx4){0.f, 0.f, 0.f, 0.f};

  GEMM_KLOOP(Abase, Bbase)

  #pragma unroll
  for (int i = 0; i < 4; i++)
    #pragma unroll
    for (int j = 0; j < 4; j++)
      #pragma unroll
      for (int r = 0; r < 4; r++) {
        int m = m0 + wm + i * 16 + quad * 4 + r;
        int n = n0 + wn + j * 16 + r16;
        C[(size_t)m * D_ + n] = acc[i][j][r];
      }
}

// ---------------- Flash attention v4: S^T formulation, no P round-trip ----
// Block: 64 q rows (4 waves x 16 q). Grid (16,32,2); pairing {31-bx, bx}
// -> 33 iters/block uniform. K/V staged via swizzled global_load_lds into
// unpadded 64x64 tiles (16 KB total -> 4 blocks/CU).
// S^T = K·Q^T (A=K, B=Q): C-layout lane holds (q=r16, k=quad*4+reg) ==
// A-operand layout of mfma 16x16x16 -> P feeds PV straight from registers.
// Static-max softmax (|s|*SCALE <= 8); l is a per-lane scalar (q=r16).
#define LOG2E 1.44269504089f

__global__ __launch_bounds__(256) void attn(const uint16_t* __restrict__ qb,
                                            const uint16_t* __restrict__ kb,
                                            const uint16_t* __restrict__ vtb,
                                            uint16_t* __restrict__ ao) {
  const int tid = threadIdx.x;
  const int wave = tid >> 6, lane = tid & 63;
  const int quad = lane >> 4, r16 = lane & 15;
  const int h = blockIdx.y, b = blockIdx.z;
  const int kvh = h >> 2;

  const uint16_t* Q  = qb  + ((size_t)b * H_ + h) * T_ * HD_;
  const uint16_t* K  = kb  + ((size_t)b * HKV_ + kvh) * T_ * HD_;
  const uint16_t* Vt = vtb + ((size_t)b * HKV_ + kvh) * (size_t)HD_ * T_;

  __shared__ __align__(16) uint16_t Kl[64 * 64];
  __shared__ __align__(16) uint16_t Vl[64 * 64];

  for (int pass = 0; pass < 2; pass++) {
    const int qt = pass ? (int)blockIdx.x : 31 - (int)blockIdx.x;
    const int q0 = qt * 64;
    const int Rw = q0 + wave * 16;  // wave's 16 q rows

    // Q B-frags: B[n=q=r16][kk=quad*8+j], two 32-d halves
    bf16x8 bq[2];
    #pragma unroll
    for (int hh = 0; hh < 2; hh++)
      bq[hh] = *(const bf16x8*)(Q + (size_t)(Rw + r16) * HD_ + hh * 32 + quad * 8);

    floatx4 o[4];  // [d-chunk]; lane holds (q=quad*4+reg, d=jn*16+r16)
    float l = 0.f; // row sum for q = r16
    #pragma unroll
    for (int jn = 0; jn < 4; jn++) o[jn] = (floatx4){0.f, 0.f, 0.f, 0.f};

    const int iters = qt + 1;
    for (int it = 0; it < iters; it++) {
      const int kt = it * 64;
      // ---- stage K rows (t,d) and Vt rows (d,t), swizzled, async ----
      __syncthreads();
#ifdef HAVE_ASYNC_LDS
      #pragma unroll
      for (int c = 0; c < 2; c++) {
        int row = wave * 16 + c * 8 + (lane >> 3);
        int cg  = (lane & 7) ^ ((lane >> 3) & 7);
        g2lds16(K  + (size_t)(kt + row) * HD_ + cg * 8, Kl + (wave * 16 + c * 8) * 64 + lane * 8);
        g2lds16(Vt + (size_t)row * T_ + kt + cg * 8,    Vl + (wave * 16 + c * 8) * 64 + lane * 8);
      }
#else
      #pragma unroll
      for (int c = 0; c < 2; c++) {
        int row = wave * 16 + c * 8 + (lane >> 3);
        int cg  = (lane & 7) ^ ((lane >> 3) & 7);
        *(uint4*)&Kl[(wave * 16 + c * 8) * 64 + lane * 8] =
            *(const uint4*)(K + (size_t)(kt + row) * HD_ + cg * 8);
        *(uint4*)&Vl[(wave * 16 + c * 8) * 64 + lane * 8] =
            *(const uint4*)(Vt + (size_t)row * T_ + kt + cg * 8);
      }
#endif
      __syncthreads();  // drains vmcnt(0) -> async LDS writes landed

      #pragma unroll
      for (int mt = 0; mt < 4; mt++) {
        if (kt + mt * 16 > Rw + 15) continue;  // fully-masked chunk (wave-uniform)
        // ---- S^T chunk: A = K rows (m=k-col), B = Q (n=q) ----
        bf16x8 kf0 = frag64(Kl, mt * 16 + r16, quad);
        bf16x8 kf1 = frag64(Kl, mt * 16 + r16, 4 + quad);
        floatx4 st = (floatx4){0.f, 0.f, 0.f, 0.f};
        st = mfma16(kf0, bq[0], st);
        st = mfma16(kf1, bq[1], st);
        // lane holds: q = r16, k = kt + mt*16 + quad*4 + reg
        const bool needm = (kt + mt * 16 + 15) > Rw;
        float pv[4];
        #pragma unroll
        for (int r = 0; r < 4; r++) {
          pv[r] = fast_exp2(fmaf(st[r], SCALE_ * LOG2E, -8.0f * LOG2E));
          if (needm) {
            int kcol = kt + mt * 16 + quad * 4 + r;
            if (kcol > Rw + r16) pv[r] = 0.f;
          }
          l += pv[r];
        }
        uint64_t pu = (uint64_t)f2bf_pk(pv[0], pv[1]) |
                      ((uint64_t)f2bf_pk(pv[2], pv[3]) << 32);
        bf16x4 pa = __builtin_bit_cast(bf16x4, pu);
        // ---- O += P16 · V16 : B[n=d=r16][k=quad*4+j] from swizzled Vl ----
        #pragma unroll
        for (int jn = 0; jn < 4; jn++) {
          int vrow = jn * 16 + r16;
          int pcg = (mt * 2 + (quad >> 1)) ^ (vrow & 7);
          bf16x4 vf = *(const bf16x4*)&Vl[vrow * 64 + pcg * 8 + (quad & 1) * 4];
          o[jn] = mfma16k16(pa, vf, o[jn]);
        }
      }
    }

    // ---- l: reduce over quads (lanes sharing r16), transpose to rows ----
    l += __shfl_xor(l, 16);
    l += __shfl_xor(l, 32);
    float lq[4];
    #pragma unroll
    for (int r = 0; r < 4; r++) lq[r] = __shfl(l, quad * 4 + r);  // l for q=quad*4+r

    #pragma unroll
    for (int jn = 0; jn < 4; jn++) {
      uint32_t u01 = f2bf_pk(o[jn][0] / lq[0], o[jn][1] / lq[1]);
      uint32_t u23 = f2bf_pk(o[jn][2] / lq[2], o[jn][3] / lq[3]);
      int t0 = Rw + quad * 4;
      size_t base = ((size_t)b * T_ + t0) * (H_ * HD_) + h * HD_ + jn * 16 + r16;
      ao[base]                = (uint16_t)u01;
      ao[base + 1 * H_ * HD_] = (uint16_t)(u01 >> 16);
      ao[base + 2 * H_ * HD_] = (uint16_t)u23;
      ao[base + 3 * H_ * HD_] = (uint16_t)(u23 >> 16);
    }
  }
}

extern "C" void kernel_launch(void* const* d_in, const int* in_sizes, int n_in,
                              void* d_out, int out_size, void* d_ws, size_t ws_size,
                              hipStream_t stream) {
  const float* x  = (const float*)d_in[0];
  const float* Wq = (const float*)d_in[1];
  const float* Wk = (const float*)d_in[2];
  const float* Wv = (const float*)d_in[3];
  const float* Wo = (const float*)d_in[4];
  const float* qw = (const float*)d_in[5];
  const float* kw = (const float*)d_in[6];
  float* out = (float*)d_out;

  char* ws = (char*)d_ws;
  uint16_t* xb  = (uint16_t*)(ws);               // 16 MB  x bf16 (later: ao bf16)
  uint16_t* wqb = (uint16_t*)(ws + 16777216);    // 8 MB
  uint16_t* wkb = (uint16_t*)(ws + 25165824);    // 2 MB
  uint16_t* wvb = (uint16_t*)(ws + 27262976);    // 2 MB
  uint16_t* wob = (uint16_t*)(ws + 29360128);    // 8 MB
  uint16_t* qbf = (uint16_t*)(ws + 37748736);    // 16 MB  q bf16 (b,h,t,d) post norm+rope
  uint16_t* kbf = (uint16_t*)(ws + 54525952);    // 4 MB   k bf16 (b,kvh,t,d)
  uint16_t* vtb = (uint16_t*)(ws + 58720256);    // 4 MB   V^T bf16 (b,kvh,d,t)
  uint16_t* aob = xb;

  cvt_all<<<18432, 256, 0, stream>>>(x, Wq, Wk, Wv, Wo, xb, wqb, wkb, wvb, wob);

  qkv_gemm<<<dim3(24, 32), 256, 0, stream>>>(xb, wqb, wkb, wvb, qw, kw, qbf, kbf, vtb);

  attn<<<dim3(16, 32, 2), 256, 0, stream>>>(qbf, kbf, vtb, aob);

  oproj_gemm<<<dim3(16, 32), 256, 0, stream>>>(aob, wob, out);
}

// Round 6
// 317.866 us; speedup vs baseline: 2.1406x; 1.0686x over previous
//
#include <hip/hip_runtime.h>
#include <hip/hip_bf16.h>
#include <stdint.h>

// Problem constants
#define B_ 2
#define T_ 2048
#define D_ 2048
#define H_ 32
#define HKV_ 8
#define HD_ 64
#define SCALE_ 0.125f  // HD^-0.5

typedef float floatx4 __attribute__((ext_vector_type(4)));
typedef __bf16 bf16x8 __attribute__((ext_vector_type(8)));
typedef __bf16 bf16x4 __attribute__((ext_vector_type(4)));
typedef short short4v __attribute__((ext_vector_type(4)));

__device__ inline floatx4 mfma16(bf16x8 a, bf16x8 b, floatx4 c) {
  return __builtin_amdgcn_mfma_f32_16x16x32_bf16(a, b, c, 0, 0, 0);
}

// 16x16x16 bf16 MFMA: A/B = 4 bf16/lane [m=lane&15][k=quad*4+j]; C/D same as x32.
__device__ inline floatx4 mfma16k16(bf16x4 a, bf16x4 b, floatx4 c) {
#if __has_builtin(__builtin_amdgcn_mfma_f32_16x16x16_bf16)
  return __builtin_amdgcn_mfma_f32_16x16x16_bf16(a, b, c, 0, 0, 0);
#else
  return __builtin_amdgcn_mfma_f32_16x16x16bf16_1k(
      __builtin_bit_cast(short4v, a), __builtin_bit_cast(short4v, b), c, 0, 0, 0);
#endif
}

// RNE float -> bf16 bits
__device__ inline uint16_t f2bf(float f) {
  union { float f; uint32_t u; } x; x.f = f;
  uint32_t r = x.u + 0x7fffu + ((x.u >> 16) & 1u);
  return (uint16_t)(r >> 16);
}

__device__ inline uint32_t f2bf_pk(float a, float b) {
#if __has_builtin(__builtin_amdgcn_cvt_pk_bf16_f32)
  auto pk = __builtin_amdgcn_cvt_pk_bf16_f32(a, b);
  return __builtin_bit_cast(uint32_t, pk);
#else
  return (uint32_t)f2bf(a) | ((uint32_t)f2bf(b) << 16);
#endif
}

// cheap pack for P (values in [0,1], feeding bf16 MFMA): RNE if HW op exists,
// else 1-instr v_perm truncation (bias < 0.4%, well inside threshold).
__device__ inline uint32_t pack_p(float a, float b) {
#if __has_builtin(__builtin_amdgcn_cvt_pk_bf16_f32)
  auto pk = __builtin_amdgcn_cvt_pk_bf16_f32(a, b);
  return __builtin_bit_cast(uint32_t, pk);
#else
  return __builtin_amdgcn_perm(__builtin_bit_cast(uint32_t, b),
                               __builtin_bit_cast(uint32_t, a), 0x07060302u);
#endif
}

__device__ inline float fast_exp2(float x) {
#if __has_builtin(__builtin_amdgcn_exp2f)
  return __builtin_amdgcn_exp2f(x);
#else
  return __expf(x * 0.69314718056f);
#endif
}

#if __has_builtin(__builtin_amdgcn_global_load_lds)
#define HAVE_ASYNC_LDS 1
typedef const __attribute__((address_space(1))) uint32_t* gas1_u32;
typedef __attribute__((address_space(3))) uint32_t* las3_u32;
__device__ inline void g2lds16(const uint16_t* g, uint16_t* l) {
  __builtin_amdgcn_global_load_lds((gas1_u32)(const void*)g, (las3_u32)(void*)l, 16, 0, 0);
}
#endif

// ---------------- merged fp32 -> bf16 convert (4 elems/thread) ------------
__global__ __launch_bounds__(256) void cvt_all(
    const float* __restrict__ x, const float* __restrict__ wq,
    const float* __restrict__ wk, const float* __restrict__ wv,
    const float* __restrict__ wo,
    uint16_t* __restrict__ xb, uint16_t* __restrict__ wqb,
    uint16_t* __restrict__ wkb, uint16_t* __restrict__ wvb,
    uint16_t* __restrict__ wob) {
  int i = blockIdx.x * 256 + threadIdx.x;
  const float* src; uint16_t* dst; int off;
  if (i < 2097152)      { src = x;  dst = xb;  off = i; }
  else if (i < 3145728) { src = wq; dst = wqb; off = i - 2097152; }
  else if (i < 3407872) { src = wk; dst = wkb; off = i - 3145728; }
  else if (i < 3670016) { src = wv; dst = wvb; off = i - 3407872; }
  else                  { src = wo; dst = wob; off = i - 3670016; }
  float4 v = ((const float4*)src)[off];
  uint64_t packed = (uint64_t)f2bf_pk(v.x, v.y) | ((uint64_t)f2bf_pk(v.z, v.w) << 32);
  ((uint64_t*)dst)[off] = packed;
}

// ---------------- GEMM common: swizzled BK=64 staging ----------------
#define BM 128
#define BN 128
#define BK 64

__device__ inline void stage64(const uint16_t* gbase, uint16_t* lds,
                               int k0, int wave, int lane) {
#ifdef HAVE_ASYNC_LDS
  #pragma unroll
  for (int c = 0; c < 4; c++) {
    int chunk = wave * 4 + c;
    int row = chunk * 8 + (lane >> 3);
    int cg  = (lane & 7) ^ ((lane >> 3) & 7);
    g2lds16(gbase + (size_t)row * D_ + k0 + cg * 8, lds + chunk * 512 + lane * 8);
  }
#else
  #pragma unroll
  for (int c = 0; c < 4; c++) {
    int chunk = wave * 4 + c;
    int row = chunk * 8 + (lane >> 3);
    int cg  = (lane & 7) ^ ((lane >> 3) & 7);
    *(uint4*)&lds[chunk * 512 + lane * 8] =
        *(const uint4*)(gbase + (size_t)row * D_ + k0 + cg * 8);
  }
#endif
}

__device__ inline bf16x8 frag64(const uint16_t* lds, int row, int cg) {
  int pcg = cg ^ (row & 7);
  return *(const bf16x8*)&lds[row * 64 + pcg * 8];
}

#define GEMM_KLOOP(Abase, Bbase)                                          \
  for (int k0 = 0; k0 < D_; k0 += BK) {                                   \
    __syncthreads();                                                      \
    stage64(Abase, As, k0, wave, lane);                                   \
    stage64(Bbase, Bs, k0, wave, lane);                                   \
    __syncthreads();                                                      \
    bf16x8 af[4][2], bfr[4][2];                                           \
    _Pragma("unroll")                                                     \
    for (int i = 0; i < 4; i++) {                                         \
      af[i][0] = frag64(As, wm + i * 16 + r16, quad);                     \
      af[i][1] = frag64(As, wm + i * 16 + r16, 4 + quad);                 \
    }                                                                     \
    _Pragma("unroll")                                                     \
    for (int j = 0; j < 4; j++) {                                         \
      bfr[j][0] = frag64(Bs, wn + j * 16 + r16, quad);                    \
      bfr[j][1] = frag64(Bs, wn + j * 16 + r16, 4 + quad);                \
    }                                                                     \
    _Pragma("unroll")                                                     \
    for (int i = 0; i < 4; i++)                                           \
      _Pragma("unroll")                                                   \
      for (int j = 0; j < 4; j++) {                                       \
        acc[i][j] = mfma16(af[i][0], bfr[j][0], acc[i][j]);               \
        acc[i][j] = mfma16(af[i][1], bfr[j][1], acc[i][j]);               \
      }                                                                   \
  }

// ---------------- fused QKV projection + RMSNorm + RoPE -------------------
__global__ __launch_bounds__(256) void qkv_gemm(
    const uint16_t* __restrict__ Xb, const uint16_t* __restrict__ Wqb,
    const uint16_t* __restrict__ Wkb, const uint16_t* __restrict__ Wvb,
    const float* __restrict__ qnw, const float* __restrict__ knw,
    uint16_t* __restrict__ qbf, uint16_t* __restrict__ kbf,
    uint16_t* __restrict__ vt) {
  __shared__ __align__(16) uint16_t As[BM * BK];
  __shared__ __align__(16) uint16_t Bs[BN * BK];
  const int tid = threadIdx.x;
  const int m0 = blockIdx.y * BM;
  const int n0 = blockIdx.x * BN;

  const uint16_t* Wsrc; int nbase;
  if (n0 < 2048)      { Wsrc = Wqb; nbase = 0; }
  else if (n0 < 2560) { Wsrc = Wkb; nbase = 2048; }
  else                { Wsrc = Wvb; nbase = 2560; }

  const int lane = tid & 63, wave = tid >> 6;
  const int wm = (wave >> 1) * 64, wn = (wave & 1) * 64;
  const int quad = lane >> 4, r16 = lane & 15;
  const uint16_t* Abase = Xb + (size_t)m0 * D_;
  const uint16_t* Bbase = Wsrc + (size_t)(n0 - nbase) * D_;

  floatx4 acc[4][4];
  #pragma unroll
  for (int i = 0; i < 4; i++)
    #pragma unroll
    for (int j = 0; j < 4; j++) acc[i][j] = (floatx4){0.f, 0.f, 0.f, 0.f};

  GEMM_KLOOP(Abase, Bbase)

  if (n0 < 2560) {
    const int isK = (n0 >= 2048);
    const float* nw = isK ? knw : qnw;
    const int head = (n0 - (isK ? 2048 : 0) + wn) >> 6;
    uint16_t* dst = isK ? kbf : qbf;
    const int NH = isK ? HKV_ : H_;
    float wreg[4];
    #pragma unroll
    for (int j = 0; j < 4; j++) wreg[j] = nw[j * 16 + r16];
    float freq[4];
    #pragma unroll
    for (int j = 0; j < 4; j++)
      freq[j] = exp2f((float)(j * 8 + (r16 >> 1)) * -0.0495300781f);  // 3^(-2p/64)
    #pragma unroll
    for (int i = 0; i < 4; i++) {
      #pragma unroll
      for (int r = 0; r < 4; r++) {
        float ss = 0.f;
        #pragma unroll
        for (int j = 0; j < 4; j++) ss += acc[i][j][r] * acc[i][j][r];
        #pragma unroll
        for (int off = 8; off; off >>= 1) ss += __shfl_xor(ss, off);
        float inv = rsqrtf(ss * (1.0f / HD_) + 1e-6f);
        int m = m0 + wm + i * 16 + quad * 4 + r;
        int b = m >> 11, t = m & (T_ - 1);
        size_t rowbase = (((size_t)b * NH + head) * T_ + t) * HD_;
        #pragma unroll
        for (int j = 0; j < 4; j++) {
          float vn = acc[i][j][r] * inv * wreg[j];
          float other = __shfl_xor(vn, 1);
          float f = (float)t * freq[j];
          float s, c;
          __sincosf(f, &s, &c);
          float outv = (r16 & 1) ? (other * s + vn * c) : (vn * c - other * s);
          dst[rowbase + j * 16 + r16] = f2bf(outv);
        }
      }
    }
  } else {
    #pragma unroll
    for (int i = 0; i < 4; i++)
      #pragma unroll
      for (int j = 0; j < 4; j++)
        #pragma unroll
        for (int r = 0; r < 4; r++) {
          int m = m0 + wm + i * 16 + quad * 4 + r;
          int n = n0 + wn + j * 16 + r16 - 2560;
          int b = m >> 11, t = m & (T_ - 1);
          int head = n >> 6, d = n & 63;
          vt[(((size_t)b * HKV_ + head) * HD_ + d) * T_ + t] = f2bf(acc[i][j][r]);
        }
  }
}

// ---------------- O projection GEMM: out = ao @ Wo^T ----------------------
__global__ __launch_bounds__(256) void oproj_gemm(
    const uint16_t* __restrict__ Ab, const uint16_t* __restrict__ Bb,
    float* __restrict__ C) {
  __shared__ __align__(16) uint16_t As[BM * BK];
  __shared__ __align__(16) uint16_t Bs[BN * BK];
  const int tid = threadIdx.x;
  const int m0 = blockIdx.y * BM;
  const int n0 = blockIdx.x * BN;
  const int lane = tid & 63, wave = tid >> 6;
  const int wm = (wave >> 1) * 64, wn = (wave & 1) * 64;
  const int quad = lane >> 4, r16 = lane & 15;
  const uint16_t* Abase = Ab + (size_t)m0 * D_;
  const uint16_t* Bbase = Bb + (size_t)n0 * D_;

  floatx4 acc[4][4];
  #pragma unroll
  for (int i = 0; i < 4; i++)
    #pragma unroll
    for (int j = 0; j < 4; j++) acc[i][j] = (floatx4){0.f, 0.f, 0.f, 0.f};

  GEMM_KLOOP(Abase, Bbase)

  #pragma unroll
  for (int i = 0; i < 4; i++)
    #pragma unroll
    for (int j = 0; j < 4; j++)
      #pragma unroll
      for (int r = 0; r < 4; r++) {
        int m = m0 + wm + i * 16 + quad * 4 + r;
        int n = n0 + wn + j * 16 + r16;
        C[(size_t)m * D_ + n] = acc[i][j][r];
      }
}

// ---------------- Flash attention v5 --------------------------------------
// S^T formulation (round-5-verified). New this round:
//  * causal split: iters 0..qt-1 mask/guard-free; single diagonal iter where
//    chunk mt<wave is clean and mt==wave uses loop-invariant dm[] multiply.
//  * all LDS frag addrs precomputed (imm offsets); staging ptrs strength-reduced.
//  * V swizzle pcg = cg ^ ((row>>1)&7): conflict-free b64 PV reads.
#define LOG2E 1.44269504089f

__global__ __launch_bounds__(256) void attn(const uint16_t* __restrict__ qb,
                                            const uint16_t* __restrict__ kb,
                                            const uint16_t* __restrict__ vtb,
                                            uint16_t* __restrict__ ao) {
  const int tid = threadIdx.x;
  const int wave = tid >> 6, lane = tid & 63;
  const int quad = lane >> 4, r16 = lane & 15;
  const int h = blockIdx.y, b = blockIdx.z;
  const int kvh = h >> 2;

  const uint16_t* Q  = qb  + ((size_t)b * H_ + h) * T_ * HD_;
  const uint16_t* K  = kb  + ((size_t)b * HKV_ + kvh) * T_ * HD_;
  const uint16_t* Vt = vtb + ((size_t)b * HKV_ + kvh) * (size_t)HD_ * T_;

  __shared__ __align__(16) uint16_t Kl[64 * 64];
  __shared__ __align__(16) uint16_t Vl[64 * 64];

  // ---- staging constants (K: pcg=cg^(row&7); V: pcg=cg^((row>>1)&7)) ----
  const int l3 = lane >> 3, l7 = lane & 7, l4 = lane >> 4;
  const int cgK  = l7 ^ l3;
  const int cgV0 = l7 ^ (l4 & 7);
  const int cgV1 = l7 ^ ((4 + l4) & 7);
  uint16_t* KlD0 = Kl + (wave * 16 + 0) * 64 + lane * 8;
  uint16_t* KlD1 = Kl + (wave * 16 + 8) * 64 + lane * 8;
  uint16_t* VlD0 = Vl + (wave * 16 + 0) * 64 + lane * 8;
  uint16_t* VlD1 = Vl + (wave * 16 + 8) * 64 + lane * 8;

  // ---- fragment read offsets (elements), loop-invariant ----
  const int koffE0 = r16 * 64 + ((quad)     ^ (r16 & 7)) * 8;
  const int koffE1 = r16 * 64 + ((4 + quad) ^ (r16 & 7)) * 8;
  int voffE[4];
  #pragma unroll
  for (int mt = 0; mt < 4; mt++)
    voffE[mt] = r16 * 64 + (((mt * 2 + (quad >> 1)) ^ ((r16 >> 1) & 7)) * 8) + (quad & 1) * 4;
  // diagonal-chunk mask factor: keep iff k(=quad*4+r) <= q(=r16)
  float dm[4];
  #pragma unroll
  for (int r = 0; r < 4; r++) dm[r] = (quad * 4 + r <= r16) ? 1.0f : 0.0f;

#define AT_STAGE()                                                        \
  {                                                                       \
    __syncthreads();                                                      \
    g2lds16(kg0, KlD0); g2lds16(kg1, KlD1);                               \
    g2lds16(vg0, VlD0); g2lds16(vg1, VlD1);                               \
    kg0 += 64 * HD_; kg1 += 64 * HD_; vg0 += 64; vg1 += 64;               \
    __syncthreads();                                                      \
  }
#ifndef HAVE_ASYNC_LDS
#undef AT_STAGE
#define AT_STAGE()                                                        \
  {                                                                       \
    uint4 a = *(const uint4*)kg0, bb = *(const uint4*)kg1;                \
    uint4 c = *(const uint4*)vg0, d = *(const uint4*)vg1;                 \
    __syncthreads();                                                      \
    *(uint4*)KlD0 = a; *(uint4*)KlD1 = bb;                                \
    *(uint4*)VlD0 = c; *(uint4*)VlD1 = d;                                 \
    kg0 += 64 * HD_; kg1 += 64 * HD_; vg0 += 64; vg1 += 64;               \
    __syncthreads();                                                      \
  }
#endif

#define AT_CHUNK(mt, MASKED)                                              \
  {                                                                       \
    bf16x8 kf0 = *(const bf16x8*)&Kl[koffE0 + (mt) * 1024];               \
    bf16x8 kf1 = *(const bf16x8*)&Kl[koffE1 + (mt) * 1024];               \
    floatx4 st = (floatx4){0.f, 0.f, 0.f, 0.f};                           \
    st = mfma16(kf0, bq[0], st);                                          \
    st = mfma16(kf1, bq[1], st);                                          \
    float pv[4];                                                          \
    _Pragma("unroll")                                                     \
    for (int r = 0; r < 4; r++) {                                         \
      pv[r] = fast_exp2(fmaf(st[r], SCALE_ * LOG2E, -8.0f * LOG2E));      \
      if (MASKED) pv[r] *= dm[r];                                         \
      l += pv[r];                                                         \
    }                                                                     \
    uint64_t pu = (uint64_t)pack_p(pv[0], pv[1]) |                        \
                  ((uint64_t)pack_p(pv[2], pv[3]) << 32);                 \
    bf16x4 pa = __builtin_bit_cast(bf16x4, pu);                           \
    _Pragma("unroll")                                                     \
    for (int jn = 0; jn < 4; jn++) {                                      \
      bf16x4 vf = *(const bf16x4*)&Vl[voffE[mt] + jn * 1024];             \
      o[jn] = mfma16k16(pa, vf, o[jn]);                                   \
    }                                                                     \
  }

  for (int pass = 0; pass < 2; pass++) {
    const int qt = pass ? (int)blockIdx.x : 31 - (int)blockIdx.x;
    const int q0 = qt * 64;
    const int Rw = q0 + wave * 16;

    // Q B-frags: B[n=q=r16][kk=quad*8+j], two 32-d halves
    bf16x8 bq[2];
    #pragma unroll
    for (int hh = 0; hh < 2; hh++)
      bq[hh] = *(const bf16x8*)(Q + (size_t)(Rw + r16) * HD_ + hh * 32 + quad * 8);

    floatx4 o[4];  // lane holds (q=quad*4+reg, d=jn*16+r16)
    float l = 0.f; // row sum for q=r16
    #pragma unroll
    for (int jn = 0; jn < 4; jn++) o[jn] = (floatx4){0.f, 0.f, 0.f, 0.f};

    // staging pointers for kt=0, advanced additively
    const uint16_t* kg0 = K + (size_t)(wave * 16 + l3) * HD_ + cgK * 8;
    const uint16_t* kg1 = K + (size_t)(wave * 16 + 8 + l3) * HD_ + cgK * 8;
    const uint16_t* vg0 = Vt + (size_t)(wave * 16 + l3) * T_ + cgV0 * 8;
    const uint16_t* vg1 = Vt + (size_t)(wave * 16 + 8 + l3) * T_ + cgV1 * 8;

    // ---- full iterations: mask-free for every wave ----
    for (int it = 0; it < qt; it++) {
      AT_STAGE()
      AT_CHUNK(0, false)
      AT_CHUNK(1, false)
      AT_CHUNK(2, false)
      AT_CHUNK(3, false)
    }
    // ---- diagonal iteration (kt = q0) ----
    AT_STAGE()
    #pragma unroll
    for (int mt = 0; mt < 4; mt++) {
      if (mt < wave) AT_CHUNK(mt, false)
      else if (mt == wave) AT_CHUNK(mt, true)
    }

    // ---- l: reduce over quads, transpose to rows, normalize, store ----
    l += __shfl_xor(l, 16);
    l += __shfl_xor(l, 32);
    float lq[4];
    #pragma unroll
    for (int r = 0; r < 4; r++) lq[r] = __shfl(l, quad * 4 + r);

    #pragma unroll
    for (int jn = 0; jn < 4; jn++) {
      uint32_t u01 = f2bf_pk(o[jn][0] / lq[0], o[jn][1] / lq[1]);
      uint32_t u23 = f2bf_pk(o[jn][2] / lq[2], o[jn][3] / lq[3]);
      int t0 = Rw + quad * 4;
      size_t base = ((size_t)b * T_ + t0) * (H_ * HD_) + h * HD_ + jn * 16 + r16;
      ao[base]                = (uint16_t)u01;
      ao[base + 1 * H_ * HD_] = (uint16_t)(u01 >> 16);
      ao[base + 2 * H_ * HD_] = (uint16_t)u23;
      ao[base + 3 * H_ * HD_] = (uint16_t)(u23 >> 16);
    }
  }
#undef AT_STAGE
#undef AT_CHUNK
}

extern "C" void kernel_launch(void* const* d_in, const int* in_sizes, int n_in,
                              void* d_out, int out_size, void* d_ws, size_t ws_size,
                              hipStream_t stream) {
  const float* x  = (const float*)d_in[0];
  const float* Wq = (const float*)d_in[1];
  const float* Wk = (const float*)d_in[2];
  const float* Wv = (const float*)d_in[3];
  const float* Wo = (const float*)d_in[4];
  const float* qw = (const float*)d_in[5];
  const float* kw = (const float*)d_in[6];
  float* out = (float*)d_out;

  char* ws = (char*)d_ws;
  uint16_t* xb  = (uint16_t*)(ws);               // 16 MB  x bf16 (later: ao bf16)
  uint16_t* wqb = (uint16_t*)(ws + 16777216);    // 8 MB
  uint16_t* wkb = (uint16_t*)(ws + 25165824);    // 2 MB
  uint16_t* wvb = (uint16_t*)(ws + 27262976);    // 2 MB
  uint16_t* wob = (uint16_t*)(ws + 29360128);    // 8 MB
  uint16_t* qbf = (uint16_t*)(ws + 37748736);    // 16 MB  q bf16 (b,h,t,d) post norm+rope
  uint16_t* kbf = (uint16_t*)(ws + 54525952);    // 4 MB   k bf16 (b,kvh,t,d)
  uint16_t* vtb = (uint16_t*)(ws + 58720256);    // 4 MB   V^T bf16 (b,kvh,d,t)
  uint16_t* aob = xb;

  cvt_all<<<18432, 256, 0, stream>>>(x, Wq, Wk, Wv, Wo, xb, wqb, wkb, wvb, wob);

  qkv_gemm<<<dim3(24, 32), 256, 0, stream>>>(xb, wqb, wkb, wvb, qw, kw, qbf, kbf, vtb);

  attn<<<dim3(16, 32, 2), 256, 0, stream>>>(qbf, kbf, vtb, aob);

  oproj_gemm<<<dim3(16, 32), 256, 0, stream>>>(aob, wob, out);
}

// Round 7
// 315.483 us; speedup vs baseline: 2.1568x; 1.0076x over previous
//
#include <hip/hip_runtime.h>
#include <hip/hip_bf16.h>
#include <stdint.h>

// Problem constants
#define B_ 2
#define T_ 2048
#define D_ 2048
#define H_ 32
#define HKV_ 8
#define HD_ 64
#define SCALE_ 0.125f  // HD^-0.5

typedef float floatx4 __attribute__((ext_vector_type(4)));
typedef __bf16 bf16x8 __attribute__((ext_vector_type(8)));
typedef __bf16 bf16x4 __attribute__((ext_vector_type(4)));
typedef short short4v __attribute__((ext_vector_type(4)));

__device__ inline floatx4 mfma16(bf16x8 a, bf16x8 b, floatx4 c) {
  return __builtin_amdgcn_mfma_f32_16x16x32_bf16(a, b, c, 0, 0, 0);
}

__device__ inline floatx4 mfma16k16(bf16x4 a, bf16x4 b, floatx4 c) {
#if __has_builtin(__builtin_amdgcn_mfma_f32_16x16x16_bf16)
  return __builtin_amdgcn_mfma_f32_16x16x16_bf16(a, b, c, 0, 0, 0);
#else
  return __builtin_amdgcn_mfma_f32_16x16x16bf16_1k(
      __builtin_bit_cast(short4v, a), __builtin_bit_cast(short4v, b), c, 0, 0, 0);
#endif
}

// RNE float -> bf16 bits
__device__ inline uint16_t f2bf(float f) {
  union { float f; uint32_t u; } x; x.f = f;
  uint32_t r = x.u + 0x7fffu + ((x.u >> 16) & 1u);
  return (uint16_t)(r >> 16);
}

__device__ inline uint32_t f2bf_pk(float a, float b) {
#if __has_builtin(__builtin_amdgcn_cvt_pk_bf16_f32)
  auto pk = __builtin_amdgcn_cvt_pk_bf16_f32(a, b);
  return __builtin_bit_cast(uint32_t, pk);
#else
  return (uint32_t)f2bf(a) | ((uint32_t)f2bf(b) << 16);
#endif
}

// cheap pack for P (values in [0,1]): RNE if HW op exists, else v_perm trunc.
__device__ inline uint32_t pack_p(float a, float b) {
#if __has_builtin(__builtin_amdgcn_cvt_pk_bf16_f32)
  auto pk = __builtin_amdgcn_cvt_pk_bf16_f32(a, b);
  return __builtin_bit_cast(uint32_t, pk);
#else
  return __builtin_amdgcn_perm(__builtin_bit_cast(uint32_t, b),
                               __builtin_bit_cast(uint32_t, a), 0x07060302u);
#endif
}

__device__ inline float fast_exp2(float x) {
#if __has_builtin(__builtin_amdgcn_exp2f)
  return __builtin_amdgcn_exp2f(x);
#else
  return __expf(x * 0.69314718056f);
#endif
}

#if __has_builtin(__builtin_amdgcn_global_load_lds)
#define HAVE_ASYNC_LDS 1
typedef const __attribute__((address_space(1))) uint32_t* gas1_u32;
typedef __attribute__((address_space(3))) uint32_t* las3_u32;
__device__ inline void g2lds16(const uint16_t* g, uint16_t* l) {
  __builtin_amdgcn_global_load_lds((gas1_u32)(const void*)g, (las3_u32)(void*)l, 16, 0, 0);
}
#endif

// ---------------- merged fp32 -> bf16 convert (4 elems/thread) ------------
__global__ __launch_bounds__(256) void cvt_all(
    const float* __restrict__ x, const float* __restrict__ wq,
    const float* __restrict__ wk, const float* __restrict__ wv,
    const float* __restrict__ wo,
    uint16_t* __restrict__ xb, uint16_t* __restrict__ wqb,
    uint16_t* __restrict__ wkb, uint16_t* __restrict__ wvb,
    uint16_t* __restrict__ wob) {
  int i = blockIdx.x * 256 + threadIdx.x;
  const float* src; uint16_t* dst; int off;
  if (i < 2097152)      { src = x;  dst = xb;  off = i; }
  else if (i < 3145728) { src = wq; dst = wqb; off = i - 2097152; }
  else if (i < 3407872) { src = wk; dst = wkb; off = i - 3145728; }
  else if (i < 3670016) { src = wv; dst = wvb; off = i - 3407872; }
  else                  { src = wo; dst = wob; off = i - 3670016; }
  float4 v = ((const float4*)src)[off];
  uint64_t packed = (uint64_t)f2bf_pk(v.x, v.y) | ((uint64_t)f2bf_pk(v.z, v.w) << 32);
  ((uint64_t*)dst)[off] = packed;
}

// ---------------- GEMM common: double-buffered BK=32 ----------------------
// 128x128 tile. Each K-iter stages 128x32 A + 128x32 B (16 KB) into the
// ALTERNATE buffer right after the barrier that publishes the current one:
// async global_load_lds has the whole compute phase to fly; the next
// barrier's vmcnt(0) drain then costs ~max(0, latency - compute).
// Swizzle: element (row, cg) at physical cg^((row>>1)&3) -> balanced
// 8 lanes per 4-bank group on every b128 frag read (conflict-free).
#define BM 128
#define BN 128

// frag read: logical col-group = quad (K=32 covered by one bf16x8)
__device__ inline bf16x8 frag32(const uint16_t* lds, int row, int quad) {
  int pcg = quad ^ ((row >> 1) & 3);
  return *(const bf16x8*)&lds[row * 32 + pcg * 8];
}

// Per-thread staging geometry: slot s = c*256 + tid (c in {0,1}), 8 elems.
// row = s>>2 (=c*64 + tid>>2), pcg = tid&3, logical cg = pcg^((row>>1)&3)
// = (tid&3)^((tid>>3)&3). LDS dst = buf + s*8 (wave-uniform base + lane*16B).

#define GEMM_PROLOGUE()                                                    \
  const int srow = tid >> 2;                                               \
  const int scg = (tid & 3) ^ ((tid >> 3) & 3);                            \
  const uint16_t* gA0 = Abase + (size_t)srow * D_ + scg * 8;               \
  const uint16_t* gA1 = gA0 + (size_t)64 * D_;                             \
  const uint16_t* gB0 = Bbase + (size_t)srow * D_ + scg * 8;               \
  const uint16_t* gB1 = gB0 + (size_t)64 * D_;                             \
  uint16_t* lA[2] = {As + tid * 8, As + 4096 + tid * 8};                   \
  uint16_t* lB[2] = {Bs + tid * 8, Bs + 4096 + tid * 8};

#ifdef HAVE_ASYNC_LDS
#define GEMM_STAGE(buf, k)                                                 \
  { g2lds16(gA0 + (k), lA[buf]); g2lds16(gA1 + (k), lA[buf] + 2048);       \
    g2lds16(gB0 + (k), lB[buf]); g2lds16(gB1 + (k), lB[buf] + 2048); }
#else
#define GEMM_STAGE(buf, k)                                                 \
  { *(uint4*)lA[buf] = *(const uint4*)(gA0 + (k));                         \
    *(uint4*)(lA[buf] + 2048) = *(const uint4*)(gA1 + (k));                \
    *(uint4*)lB[buf] = *(const uint4*)(gB0 + (k));                         \
    *(uint4*)(lB[buf] + 2048) = *(const uint4*)(gB1 + (k)); }
#endif

#define GEMM_KLOOP()                                                       \
  GEMM_PROLOGUE()                                                          \
  GEMM_STAGE(0, 0)                                                         \
  int cur = 0;                                                             \
  for (int k0 = 0; k0 < D_; k0 += 32) {                                    \
    __syncthreads();                                                       \
    if (k0 + 32 < D_) { GEMM_STAGE(cur ^ 1, k0 + 32) }                     \
    const uint16_t* Ac = As + cur * 4096;                                  \
    const uint16_t* Bc = Bs + cur * 4096;                                  \
    bf16x8 af[4], bfr[4];                                                  \
    _Pragma("unroll")                                                      \
    for (int i = 0; i < 4; i++) af[i] = frag32(Ac, wm + i * 16 + r16, quad); \
    _Pragma("unroll")                                                      \
    for (int j = 0; j < 4; j++) bfr[j] = frag32(Bc, wn + j * 16 + r16, quad); \
    _Pragma("unroll")                                                      \
    for (int i = 0; i < 4; i++)                                            \
      _Pragma("unroll")                                                    \
      for (int j = 0; j < 4; j++)                                          \
        acc[i][j] = mfma16(af[i], bfr[j], acc[i][j]);                      \
    cur ^= 1;                                                              \
  }

// ---------------- fused QKV projection + RMSNorm + RoPE -------------------
__global__ __launch_bounds__(256) void qkv_gemm(
    const uint16_t* __restrict__ Xb, const uint16_t* __restrict__ Wqb,
    const uint16_t* __restrict__ Wkb, const uint16_t* __restrict__ Wvb,
    const float* __restrict__ qnw, const float* __restrict__ knw,
    uint16_t* __restrict__ qbf, uint16_t* __restrict__ kbf,
    uint16_t* __restrict__ vt) {
  __shared__ __align__(16) uint16_t As[2 * BM * 32];
  __shared__ __align__(16) uint16_t Bs[2 * BN * 32];
  const int tid = threadIdx.x;
  const int m0 = blockIdx.y * BM;
  const int n0 = blockIdx.x * BN;

  const uint16_t* Wsrc; int nbase;
  if (n0 < 2048)      { Wsrc = Wqb; nbase = 0; }
  else if (n0 < 2560) { Wsrc = Wkb; nbase = 2048; }
  else                { Wsrc = Wvb; nbase = 2560; }

  const int lane = tid & 63, wave = tid >> 6;
  const int wm = (wave >> 1) * 64, wn = (wave & 1) * 64;
  const int quad = lane >> 4, r16 = lane & 15;
  const uint16_t* Abase = Xb + (size_t)m0 * D_;
  const uint16_t* Bbase = Wsrc + (size_t)(n0 - nbase) * D_;

  floatx4 acc[4][4];
  #pragma unroll
  for (int i = 0; i < 4; i++)
    #pragma unroll
    for (int j = 0; j < 4; j++) acc[i][j] = (floatx4){0.f, 0.f, 0.f, 0.f};

  GEMM_KLOOP()

  if (n0 < 2560) {
    const int isK = (n0 >= 2048);
    const float* nw = isK ? knw : qnw;
    const int head = (n0 - (isK ? 2048 : 0) + wn) >> 6;
    uint16_t* dst = isK ? kbf : qbf;
    const int NH = isK ? HKV_ : H_;
    float wreg[4];
    #pragma unroll
    for (int j = 0; j < 4; j++) wreg[j] = nw[j * 16 + r16];
    float freq[4];
    #pragma unroll
    for (int j = 0; j < 4; j++)
      freq[j] = exp2f((float)(j * 8 + (r16 >> 1)) * -0.0495300781f);  // 3^(-2p/64)
    #pragma unroll
    for (int i = 0; i < 4; i++) {
      #pragma unroll
      for (int r = 0; r < 4; r++) {
        float ss = 0.f;
        #pragma unroll
        for (int j = 0; j < 4; j++) ss += acc[i][j][r] * acc[i][j][r];
        #pragma unroll
        for (int off = 8; off; off >>= 1) ss += __shfl_xor(ss, off);
        float inv = rsqrtf(ss * (1.0f / HD_) + 1e-6f);
        int m = m0 + wm + i * 16 + quad * 4 + r;
        int b = m >> 11, t = m & (T_ - 1);
        size_t rowbase = (((size_t)b * NH + head) * T_ + t) * HD_;
        #pragma unroll
        for (int j = 0; j < 4; j++) {
          float vn = acc[i][j][r] * inv * wreg[j];
          float other = __shfl_xor(vn, 1);
          float f = (float)t * freq[j];
          float s, c;
          __sincosf(f, &s, &c);
          float outv = (r16 & 1) ? (other * s + vn * c) : (vn * c - other * s);
          dst[rowbase + j * 16 + r16] = f2bf(outv);
        }
      }
    }
  } else {
    #pragma unroll
    for (int i = 0; i < 4; i++)
      #pragma unroll
      for (int j = 0; j < 4; j++)
        #pragma unroll
        for (int r = 0; r < 4; r++) {
          int m = m0 + wm + i * 16 + quad * 4 + r;
          int n = n0 + wn + j * 16 + r16 - 2560;
          int b = m >> 11, t = m & (T_ - 1);
          int head = n >> 6, d = n & 63;
          vt[(((size_t)b * HKV_ + head) * HD_ + d) * T_ + t] = f2bf(acc[i][j][r]);
        }
  }
}

// ---------------- O projection GEMM: out = ao @ Wo^T ----------------------
__global__ __launch_bounds__(256) void oproj_gemm(
    const uint16_t* __restrict__ Ab, const uint16_t* __restrict__ Bb,
    float* __restrict__ C) {
  __shared__ __align__(16) uint16_t As[2 * BM * 32];
  __shared__ __align__(16) uint16_t Bs[2 * BN * 32];
  const int tid = threadIdx.x;
  const int m0 = blockIdx.y * BM;
  const int n0 = blockIdx.x * BN;
  const int lane = tid & 63, wave = tid >> 6;
  const int wm = (wave >> 1) * 64, wn = (wave & 1) * 64;
  const int quad = lane >> 4, r16 = lane & 15;
  const uint16_t* Abase = Ab + (size_t)m0 * D_;
  const uint16_t* Bbase = Bb + (size_t)n0 * D_;

  floatx4 acc[4][4];
  #pragma unroll
  for (int i = 0; i < 4; i++)
    #pragma unroll
    for (int j = 0; j < 4; j++) acc[i][j] = (floatx4){0.f, 0.f, 0.f, 0.f};

  GEMM_KLOOP()

  #pragma unroll
  for (int i = 0; i < 4; i++)
    #pragma unroll
    for (int j = 0; j < 4; j++)
      #pragma unroll
      for (int r = 0; r < 4; r++) {
        int m = m0 + wm + i * 16 + quad * 4 + r;
        int n = n0 + wn + j * 16 + r16;
        C[(size_t)m * D_ + n] = acc[i][j][r];
      }
}

// ---------------- Flash attention v6: S^T + double-buffered staging -------
// Same S^T/causal-split structure as round 6; K/V tiles now double-buffered
// with the prefetch issued right after each barrier (single barrier/iter).
#define LOG2E 1.44269504089f

__global__ __launch_bounds__(256) void attn(const uint16_t* __restrict__ qb,
                                            const uint16_t* __restrict__ kb,
                                            const uint16_t* __restrict__ vtb,
                                            uint16_t* __restrict__ ao) {
  const int tid = threadIdx.x;
  const int wave = tid >> 6, lane = tid & 63;
  const int quad = lane >> 4, r16 = lane & 15;
  const int h = blockIdx.y, b = blockIdx.z;
  const int kvh = h >> 2;

  const uint16_t* Q  = qb  + ((size_t)b * H_ + h) * T_ * HD_;
  const uint16_t* K  = kb  + ((size_t)b * HKV_ + kvh) * T_ * HD_;
  const uint16_t* Vt = vtb + ((size_t)b * HKV_ + kvh) * (size_t)HD_ * T_;

  __shared__ __align__(16) uint16_t Kl[2][64 * 64];
  __shared__ __align__(16) uint16_t Vl[2][64 * 64];

  // staging constants (K: pcg=cg^(row&7); V: pcg=cg^((row>>1)&7))
  const int l3 = lane >> 3, l7 = lane & 7, l4 = lane >> 4;
  const int cgK  = l7 ^ l3;
  const int cgV0 = l7 ^ (l4 & 7);
  const int cgV1 = l7 ^ ((4 + l4) & 7);
  const int sOff = wave * 16 * 64 + lane * 8;  // dst for row block 0; +512 for block 1

  // fragment read offsets (elements), loop-invariant
  const int koffE0 = r16 * 64 + ((quad)     ^ (r16 & 7)) * 8;
  const int koffE1 = r16 * 64 + ((4 + quad) ^ (r16 & 7)) * 8;
  int voffE[4];
  #pragma unroll
  for (int mt = 0; mt < 4; mt++)
    voffE[mt] = r16 * 64 + (((mt * 2 + (quad >> 1)) ^ ((r16 >> 1) & 7)) * 8) + (quad & 1) * 4;
  float dm[4];
  #pragma unroll
  for (int r = 0; r < 4; r++) dm[r] = (quad * 4 + r <= r16) ? 1.0f : 0.0f;

#ifdef HAVE_ASYNC_LDS
#define AT_STAGE(buf)                                                     \
  { g2lds16(kg0, &Kl[buf][sOff]); g2lds16(kg1, &Kl[buf][sOff + 512]);     \
    g2lds16(vg0, &Vl[buf][sOff]); g2lds16(vg1, &Vl[buf][sOff + 512]);     \
    kg0 += 64 * HD_; kg1 += 64 * HD_; vg0 += 64; vg1 += 64; }
#else
#define AT_STAGE(buf)                                                     \
  { *(uint4*)&Kl[buf][sOff] = *(const uint4*)kg0;                         \
    *(uint4*)&Kl[buf][sOff + 512] = *(const uint4*)kg1;                   \
    *(uint4*)&Vl[buf][sOff] = *(const uint4*)vg0;                         \
    *(uint4*)&Vl[buf][sOff + 512] = *(const uint4*)vg1;                   \
    kg0 += 64 * HD_; kg1 += 64 * HD_; vg0 += 64; vg1 += 64; }
#endif

#define AT_CHUNK(mt, MASKED)                                              \
  {                                                                       \
    bf16x8 kf0 = *(const bf16x8*)&Kc[koffE0 + (mt) * 1024];               \
    bf16x8 kf1 = *(const bf16x8*)&Kc[koffE1 + (mt) * 1024];               \
    floatx4 st = (floatx4){0.f, 0.f, 0.f, 0.f};                           \
    st = mfma16(kf0, bq[0], st);                                          \
    st = mfma16(kf1, bq[1], st);                                          \
    float pv[4];                                                          \
    _Pragma("unroll")                                                     \
    for (int r = 0; r < 4; r++) {                                         \
      pv[r] = fast_exp2(fmaf(st[r], SCALE_ * LOG2E, -8.0f * LOG2E));      \
      if (MASKED) pv[r] *= dm[r];                                         \
      l += pv[r];                                                         \
    }                                                                     \
    uint64_t pu = (uint64_t)pack_p(pv[0], pv[1]) |                        \
                  ((uint64_t)pack_p(pv[2], pv[3]) << 32);                 \
    bf16x4 pa = __builtin_bit_cast(bf16x4, pu);                           \
    _Pragma("unroll")                                                     \
    for (int jn = 0; jn < 4; jn++) {                                      \
      bf16x4 vf = *(const bf16x4*)&Vc[voffE[mt] + jn * 1024];             \
      o[jn] = mfma16k16(pa, vf, o[jn]);                                   \
    }                                                                     \
  }

  for (int pass = 0; pass < 2; pass++) {
    const int qt = pass ? (int)blockIdx.x : 31 - (int)blockIdx.x;
    const int q0 = qt * 64;
    const int Rw = q0 + wave * 16;

    bf16x8 bq[2];
    #pragma unroll
    for (int hh = 0; hh < 2; hh++)
      bq[hh] = *(const bf16x8*)(Q + (size_t)(Rw + r16) * HD_ + hh * 32 + quad * 8);

    floatx4 o[4];
    float l = 0.f;
    #pragma unroll
    for (int jn = 0; jn < 4; jn++) o[jn] = (floatx4){0.f, 0.f, 0.f, 0.f};

    const uint16_t* kg0 = K + (size_t)(wave * 16 + l3) * HD_ + cgK * 8;
    const uint16_t* kg1 = K + (size_t)(wave * 16 + 8 + l3) * HD_ + cgK * 8;
    const uint16_t* vg0 = Vt + (size_t)(wave * 16 + l3) * T_ + cgV0 * 8;
    const uint16_t* vg1 = Vt + (size_t)(wave * 16 + 8 + l3) * T_ + cgV1 * 8;

    __syncthreads();  // all readers of both buffers (prev pass) done
    AT_STAGE(0)
    int cur = 0;

    // full iterations (mask-free for every wave), prefetching it+1
    for (int it = 0; it < qt; it++) {
      __syncthreads();          // publishes buf[cur]; drains this wave's stage ops
      AT_STAGE(cur ^ 1)         // prefetch it+1 (always valid: it+1 <= qt)
      const uint16_t* Kc = Kl[cur];
      const uint16_t* Vc = Vl[cur];
      AT_CHUNK(0, false)
      AT_CHUNK(1, false)
      AT_CHUNK(2, false)
      AT_CHUNK(3, false)
      cur ^= 1;
    }
    // diagonal iteration (kt = q0)
    __syncthreads();
    {
      const uint16_t* Kc = Kl[cur];
      const uint16_t* Vc = Vl[cur];
      #pragma unroll
      for (int mt = 0; mt < 4; mt++) {
        if (mt < wave) AT_CHUNK(mt, false)
        else if (mt == wave) AT_CHUNK(mt, true)
      }
    }

    // l: reduce over quads, transpose to rows, normalize, store
    l += __shfl_xor(l, 16);
    l += __shfl_xor(l, 32);
    float lq[4];
    #pragma unroll
    for (int r = 0; r < 4; r++) lq[r] = __shfl(l, quad * 4 + r);

    #pragma unroll
    for (int jn = 0; jn < 4; jn++) {
      uint32_t u01 = f2bf_pk(o[jn][0] / lq[0], o[jn][1] / lq[1]);
      uint32_t u23 = f2bf_pk(o[jn][2] / lq[2], o[jn][3] / lq[3]);
      int t0 = Rw + quad * 4;
      size_t base = ((size_t)b * T_ + t0) * (H_ * HD_) + h * HD_ + jn * 16 + r16;
      ao[base]                = (uint16_t)u01;
      ao[base + 1 * H_ * HD_] = (uint16_t)(u01 >> 16);
      ao[base + 2 * H_ * HD_] = (uint16_t)u23;
      ao[base + 3 * H_ * HD_] = (uint16_t)(u23 >> 16);
    }
  }
#undef AT_STAGE
#undef AT_CHUNK
}

extern "C" void kernel_launch(void* const* d_in, const int* in_sizes, int n_in,
                              void* d_out, int out_size, void* d_ws, size_t ws_size,
                              hipStream_t stream) {
  const float* x  = (const float*)d_in[0];
  const float* Wq = (const float*)d_in[1];
  const float* Wk = (const float*)d_in[2];
  const float* Wv = (const float*)d_in[3];
  const float* Wo = (const float*)d_in[4];
  const float* qw = (const float*)d_in[5];
  const float* kw = (const float*)d_in[6];
  float* out = (float*)d_out;

  char* ws = (char*)d_ws;
  uint16_t* xb  = (uint16_t*)(ws);               // 16 MB  x bf16 (later: ao bf16)
  uint16_t* wqb = (uint16_t*)(ws + 16777216);    // 8 MB
  uint16_t* wkb = (uint16_t*)(ws + 25165824);    // 2 MB
  uint16_t* wvb = (uint16_t*)(ws + 27262976);    // 2 MB
  uint16_t* wob = (uint16_t*)(ws + 29360128);    // 8 MB
  uint16_t* qbf = (uint16_t*)(ws + 37748736);    // 16 MB  q bf16 (b,h,t,d) post norm+rope
  uint16_t* kbf = (uint16_t*)(ws + 54525952);    // 4 MB   k bf16 (b,kvh,t,d)
  uint16_t* vtb = (uint16_t*)(ws + 58720256);    // 4 MB   V^T bf16 (b,kvh,d,t)
  uint16_t* aob = xb;

  cvt_all<<<18432, 256, 0, stream>>>(x, Wq, Wk, Wv, Wo, xb, wqb, wkb, wvb, wob);

  qkv_gemm<<<dim3(24, 32), 256, 0, stream>>>(xb, wqb, wkb, wvb, qw, kw, qbf, kbf, vtb);

  attn<<<dim3(16, 32, 2), 256, 0, stream>>>(qbf, kbf, vtb, aob);

  oproj_gemm<<<dim3(16, 32), 256, 0, stream>>>(aob, wob, out);
}